// Round 5
// baseline (2996.326 us; speedup 1.0000x reference)
//
#include <hip/hip_runtime.h>

#define N_NODES 50000
#define N_EDGES 800000
#define NF 128

// ---------------- degree kernels ----------------

__global__ __launch_bounds__(256)
void k_deg_init(float* __restrict__ deg) {
    int i = blockIdx.x * 256 + threadIdx.x;
    if (i < N_NODES) deg[i] = 1.0f;   // self-loop contributes 1
}

__global__ __launch_bounds__(256)
void k_deg_count(const int* __restrict__ dst, float* __restrict__ deg) {
    int e = blockIdx.x * 256 + threadIdx.x;
    if (e < N_EDGES) atomicAdd(&deg[dst[e]], 1.0f);
}

__global__ __launch_bounds__(256)
void k_deg_finalize(float* __restrict__ deg) {
    int i = blockIdx.x * 256 + threadIdx.x;
    if (i < N_NODES) deg[i] = 1.0f / sqrtf(deg[i]);
}

// ---------------- scatter-aggregate ----------------
// agg[dst] += dis[src]*dis[dst] * feat[src], over E real edges + N self loops.
// 32 lanes per edge, each lane handles one float4 (128 feats).

__global__ __launch_bounds__(256)
void k_scatter(const int* __restrict__ src, const int* __restrict__ dst,
               const float* __restrict__ dis, const float* __restrict__ feat,
               float* __restrict__ agg) {
    const int lane = threadIdx.x & 31;
    int e = blockIdx.x * 8 + (threadIdx.x >> 5);
    if (e >= N_EDGES + N_NODES) return;
    int s, d;
    if (e < N_EDGES) { s = src[e]; d = dst[e]; }
    else             { s = e - N_EDGES; d = s; }
    float norm = dis[s] * dis[d];
    float4 v = ((const float4*)(feat + (size_t)s * NF))[lane];
    float* o = agg + (size_t)d * NF + lane * 4;
    atomicAdd(o + 0, norm * v.x);
    atomicAdd(o + 1, norm * v.y);
    atomicAdd(o + 2, norm * v.z);
    atomicAdd(o + 3, norm * v.w);
}

// ---------------- fp32 GEMM  C = A @ W (+epilogue) ----------------
// A: [N][128], W: [128][128] row-major, tile = 64 rows x 128 cols per block.
// 256 threads: tx = t&31 -> 4 cols, ty = t>>5 -> 8 rows. 32 accs/thread.
// A tile staged in LDS (33.8 KB); W read via L1/L2 (64 KB, cache-resident).
// MODE 0: C = acc + bias
// MODE 1: C = relu(acc + bias) + skip

template <int MODE>
__global__ __launch_bounds__(256)
void k_gemm(const float* __restrict__ A, const float* __restrict__ W,
            const float* __restrict__ bias, const float* __restrict__ skip,
            float* __restrict__ C) {
    __shared__ float xs[64 * 132];
    const int t = threadIdx.x;
    const int row0 = blockIdx.x * 64;

    // stage A tile: 64 rows x 32 float4
#pragma unroll
    for (int i = 0; i < 8; i++) {
        int idx = t + i * 256;          // 0..2047
        int r = idx >> 5, c4 = idx & 31;
        float4 v = make_float4(0.f, 0.f, 0.f, 0.f);
        if (row0 + r < N_NODES)
            v = ((const float4*)(A + (size_t)(row0 + r) * NF))[c4];
        *(float4*)(xs + r * 132 + c4 * 4) = v;
    }
    __syncthreads();

    const int tx = t & 31, ty = t >> 5;
    const int col = tx * 4;
    float acc[8][4];
#pragma unroll
    for (int r = 0; r < 8; r++)
#pragma unroll
        for (int j = 0; j < 4; j++) acc[r][j] = 0.f;

#pragma unroll 8
    for (int k0 = 0; k0 < 128; k0 += 4) {
        float4 w0 = *(const float4*)(W + (size_t)(k0 + 0) * NF + col);
        float4 w1 = *(const float4*)(W + (size_t)(k0 + 1) * NF + col);
        float4 w2 = *(const float4*)(W + (size_t)(k0 + 2) * NF + col);
        float4 w3 = *(const float4*)(W + (size_t)(k0 + 3) * NF + col);
#pragma unroll
        for (int r = 0; r < 8; r++) {
            float4 a = *(const float4*)(xs + (ty * 8 + r) * 132 + k0);
            acc[r][0] += a.x * w0.x + a.y * w1.x + a.z * w2.x + a.w * w3.x;
            acc[r][1] += a.x * w0.y + a.y * w1.y + a.z * w2.y + a.w * w3.y;
            acc[r][2] += a.x * w0.z + a.y * w1.z + a.z * w2.z + a.w * w3.z;
            acc[r][3] += a.x * w0.w + a.y * w1.w + a.z * w2.w + a.w * w3.w;
        }
    }

    float4 b = *(const float4*)(bias + col);
#pragma unroll
    for (int r = 0; r < 8; r++) {
        int row = row0 + ty * 8 + r;
        if (row < N_NODES) {
            float4 o;
            o.x = acc[r][0] + b.x;
            o.y = acc[r][1] + b.y;
            o.z = acc[r][2] + b.z;
            o.w = acc[r][3] + b.w;
            if (MODE == 1) {
                float4 s4 = *(const float4*)(skip + (size_t)row * NF + col);
                o.x = fmaxf(o.x, 0.f) + s4.x;
                o.y = fmaxf(o.y, 0.f) + s4.y;
                o.z = fmaxf(o.z, 0.f) + s4.z;
                o.w = fmaxf(o.w, 0.f) + s4.w;
            }
            *(float4*)(C + (size_t)row * NF + col) = o;
        }
    }
}

// ---------------- launch ----------------

extern "C" void kernel_launch(void* const* d_in, const int* in_sizes, int n_in,
                              void* d_out, int out_size, void* d_ws, size_t ws_size,
                              hipStream_t stream) {
    const int*   ei = (const int*)d_in[0];
    const float* x  = (const float*)d_in[1];
    const float* W1 = (const float*)d_in[2];
    const float* b1 = (const float*)d_in[3];
    const float* W2 = (const float*)d_in[4];
    const float* b2 = (const float*)d_in[5];
    float* out = (float*)d_out;

    const int* src = ei;             // edge_index[0]
    const int* dst = ei + N_EDGES;   // edge_index[1]

    float* dis  = (float*)d_ws;                                  // [N]
    float* buf1 = (float*)((char*)d_ws + ((N_NODES * 4 + 511) / 512) * 512); // [N*128]

    const size_t featbytes = (size_t)N_NODES * NF * sizeof(float);
    const int nblk = (N_NODES + 255) / 256;
    const int eblk = (N_EDGES + 255) / 256;
    const int sc_blocks = (N_EDGES + N_NODES + 7) / 8;
    const int gemm_blocks = (N_NODES + 63) / 64;

    // degrees -> dis = 1/sqrt(deg)
    k_deg_init<<<nblk, 256, 0, stream>>>(dis);
    k_deg_count<<<eblk, 256, 0, stream>>>(dst, dis);
    k_deg_finalize<<<nblk, 256, 0, stream>>>(dis);

    // layer 1: agg_x = scatter(norm * x); h2 = relu(agg_x@W1 + b1) + x -> d_out
    hipMemsetAsync(buf1, 0, featbytes, stream);
    k_scatter<<<sc_blocks, 256, 0, stream>>>(src, dst, dis, x, buf1);
    k_gemm<1><<<gemm_blocks, 256, 0, stream>>>(buf1, W1, b1, x, out);

    // layer 2: agg_h = scatter(norm * h2); out = agg_h@W2 + b2 -> d_out
    hipMemsetAsync(buf1, 0, featbytes, stream);
    k_scatter<<<sc_blocks, 256, 0, stream>>>(src, dst, dis, out, buf1);
    k_gemm<0><<<gemm_blocks, 256, 0, stream>>>(buf1, W2, b2, nullptr, out);
}

// Round 6
// 493.841 us; speedup vs baseline: 6.0674x; 6.0674x over previous
//
#include <hip/hip_runtime.h>

#define N_NODES 50000
#define N_EDGES 800000
#define NF 128
#define SCAN_T 1024
#define CHUNK 49   // ceil(50000/1024)

// ---------------- CSR build ----------------

__global__ __launch_bounds__(256)
void k_count(const int* __restrict__ dst, int* __restrict__ cnt) {
    int e = blockIdx.x * 256 + threadIdx.x;
    if (e < N_EDGES) atomicAdd(&cnt[dst[e]], 1);
}

__global__ __launch_bounds__(256)
void k_dis(const int* __restrict__ cnt, float* __restrict__ dis) {
    int i = blockIdx.x * 256 + threadIdx.x;
    if (i < N_NODES) dis[i] = rsqrtf((float)(1 + cnt[i]));  // +1 self loop
}

// exclusive scan of cnt[0..N) -> row_start[0..N]; also primes cursor.
// NOTE: cnt may alias cursor (phase A reads & phase C reads-then-writes are
// separated by __syncthreads, and phase C reads each idx before writing it).
__global__ __launch_bounds__(SCAN_T)
void k_scan(const int* __restrict__ cnt, int* __restrict__ row_start,
            int* __restrict__ cursor) {
    __shared__ int ps[SCAN_T];
    const int t = threadIdx.x;
    const int base = t * CHUNK;
    int s = 0;
    for (int i = 0; i < CHUNK; i++) {
        int idx = base + i;
        if (idx < N_NODES) s += cnt[idx];
    }
    ps[t] = s;
    __syncthreads();
    const int my = s;
    for (int off = 1; off < SCAN_T; off <<= 1) {
        int v = (t >= off) ? ps[t - off] : 0;
        __syncthreads();
        ps[t] += v;
        __syncthreads();
    }
    int run = ps[t] - my;   // exclusive prefix of this chunk
    for (int i = 0; i < CHUNK; i++) {
        int idx = base + i;
        if (idx < N_NODES) {
            int c = cnt[idx];          // read BEFORE cursor write (alias-safe)
            row_start[idx] = run;
            cursor[idx] = run;
            run += c;
        }
    }
    if (t == SCAN_T - 1) row_start[N_NODES] = ps[t];
}

__global__ __launch_bounds__(256)
void k_fill(const int* __restrict__ src, const int* __restrict__ dst,
            int* __restrict__ cursor, int* __restrict__ csr_src) {
    int e = blockIdx.x * 256 + threadIdx.x;
    if (e < N_EDGES) {
        int d = dst[e];
        int pos = atomicAdd(&cursor[d], 1);
        csr_src[pos] = src[e];
    }
}

// ---------------- fused gather + GEMM ----------------
// Per block: gather 64 node-rows of agg = D^-1/2 (A+I) D^-1/2 feat into LDS,
// then C[64 x 128] = xs @ W (+ epilogue).
// 512 threads = 8 waves. Gather: wave w owns 8 nodes; within a wave the two
// 32-lane halves split the edge list (lane&31 owns one float4 of 128 feats).
// MODE 0: C = acc + bias;  MODE 1: C = relu(acc + bias) + skip.

template <int MODE>
__global__ __launch_bounds__(512)
void k_fused(const int* __restrict__ row_start, const int* __restrict__ csr_src,
             const float* __restrict__ dis, const float* __restrict__ feat,
             const float* __restrict__ W, const float* __restrict__ bias,
             const float* __restrict__ skip, float* __restrict__ C) {
    __shared__ float xs[64 * 132];
    const int t = threadIdx.x;
    const int row0 = blockIdx.x * 64;

    {   // ---- gather phase ----
        const int wave = t >> 6;          // 0..7
        const int lane = t & 63;
        const int half = lane >> 5;       // 0/1: edge-list split
        const int hl = lane & 31;         // float4 slice owner
        for (int i = 0; i < 8; i++) {
            const int r = wave * 8 + i;
            const int n = row0 + r;
            float4 acc = make_float4(0.f, 0.f, 0.f, 0.f);
            if (n < N_NODES) {
                const float dn = dis[n];
                if (half == 0) {          // self loop (half 0 only)
                    float4 v = ((const float4*)(feat + (size_t)n * NF))[hl];
                    float w = dn * dn;
                    acc.x = w * v.x; acc.y = w * v.y;
                    acc.z = w * v.z; acc.w = w * v.w;
                }
                const int st = row_start[n], en = row_start[n + 1];
                for (int j = st + half; j < en; j += 2) {
                    const int s = csr_src[j];
                    const float nm = dis[s] * dn;
                    float4 f = ((const float4*)(feat + (size_t)s * NF))[hl];
                    acc.x += nm * f.x; acc.y += nm * f.y;
                    acc.z += nm * f.z; acc.w += nm * f.w;
                }
            }
            // combine halves: half1's partial -> half0
            acc.x += __shfl_down(acc.x, 32);
            acc.y += __shfl_down(acc.y, 32);
            acc.z += __shfl_down(acc.z, 32);
            acc.w += __shfl_down(acc.w, 32);
            if (half == 0) *(float4*)(xs + r * 132 + hl * 4) = acc;
        }
    }
    __syncthreads();

    // ---- GEMM phase: 512 threads, tx->4 cols, ty->4 rows ----
    const int tx = t & 31, ty = t >> 5;   // ty 0..15
    const int col = tx * 4;
    float acc[4][4];
#pragma unroll
    for (int r = 0; r < 4; r++)
#pragma unroll
        for (int j = 0; j < 4; j++) acc[r][j] = 0.f;

#pragma unroll 8
    for (int k0 = 0; k0 < 128; k0 += 4) {
        float4 w0 = *(const float4*)(W + (size_t)(k0 + 0) * NF + col);
        float4 w1 = *(const float4*)(W + (size_t)(k0 + 1) * NF + col);
        float4 w2 = *(const float4*)(W + (size_t)(k0 + 2) * NF + col);
        float4 w3 = *(const float4*)(W + (size_t)(k0 + 3) * NF + col);
#pragma unroll
        for (int r = 0; r < 4; r++) {
            float4 a = *(const float4*)(xs + (ty * 4 + r) * 132 + k0);
            acc[r][0] += a.x * w0.x + a.y * w1.x + a.z * w2.x + a.w * w3.x;
            acc[r][1] += a.x * w0.y + a.y * w1.y + a.z * w2.y + a.w * w3.y;
            acc[r][2] += a.x * w0.z + a.y * w1.z + a.z * w2.z + a.w * w3.z;
            acc[r][3] += a.x * w0.w + a.y * w1.w + a.z * w2.w + a.w * w3.w;
        }
    }

    float4 b = *(const float4*)(bias + col);
#pragma unroll
    for (int r = 0; r < 4; r++) {
        int row = row0 + ty * 4 + r;
        if (row < N_NODES) {
            float4 o;
            o.x = acc[r][0] + b.x;
            o.y = acc[r][1] + b.y;
            o.z = acc[r][2] + b.z;
            o.w = acc[r][3] + b.w;
            if (MODE == 1) {
                float4 s4 = *(const float4*)(skip + (size_t)row * NF + col);
                o.x = fmaxf(o.x, 0.f) + s4.x;
                o.y = fmaxf(o.y, 0.f) + s4.y;
                o.z = fmaxf(o.z, 0.f) + s4.z;
                o.w = fmaxf(o.w, 0.f) + s4.w;
            }
            *(float4*)(C + (size_t)row * NF + col) = o;
        }
    }
}

// ---------------- launch ----------------

extern "C" void kernel_launch(void* const* d_in, const int* in_sizes, int n_in,
                              void* d_out, int out_size, void* d_ws, size_t ws_size,
                              hipStream_t stream) {
    const int*   ei = (const int*)d_in[0];
    const float* x  = (const float*)d_in[1];
    const float* W1 = (const float*)d_in[2];
    const float* b1 = (const float*)d_in[3];
    const float* W2 = (const float*)d_in[4];
    const float* b2 = (const float*)d_in[5];
    float* out = (float*)d_out;

    const int* src = ei;             // edge_index[0]
    const int* dst = ei + N_EDGES;   // edge_index[1]

    // workspace layout (256B-aligned chunks)
    char* w = (char*)d_ws;
    float* dis       = (float*)(w);                    // [N]        200000 B
    int*   row_start = (int*)  (w + 200192);           // [N+1]      200004 B
    int*   cursor    = (int*)  (w + 400640);           // [N] (also cnt)
    int*   csr_src   = (int*)  (w + 600832);           // [E]        3.2 MB
    float* h2        = (float*)(w + 3801088);          // [N*128]    25.6 MB
    // total ~29.4 MB

    const int eblk = (N_EDGES + 255) / 256;
    const int nblk = (N_NODES + 255) / 256;
    const int fblk = (N_NODES + 63) / 64;

    // CSR build
    hipMemsetAsync(cursor, 0, N_NODES * sizeof(int), stream);    // cnt = 0
    k_count<<<eblk, 256, 0, stream>>>(dst, cursor);
    k_dis<<<nblk, 256, 0, stream>>>(cursor, dis);
    k_scan<<<1, SCAN_T, 0, stream>>>(cursor, row_start, cursor);
    k_fill<<<eblk, 256, 0, stream>>>(src, dst, cursor, csr_src);

    // layer 1: h2 = relu(gather(x)@W1 + b1) + x
    k_fused<1><<<fblk, 512, 0, stream>>>(row_start, csr_src, dis, x, W1, b1, x, h2);
    // layer 2: out = gather(h2)@W2 + b2
    k_fused<0><<<fblk, 512, 0, stream>>>(row_start, csr_src, dis, h2, W2, b2, nullptr, out);
}

// Round 7
// 440.364 us; speedup vs baseline: 6.8042x; 1.1214x over previous
//
#include <hip/hip_runtime.h>

#define N_NODES 50000
#define N_EDGES 800000
#define NF 128
#define SCAN_T 1024
#define CHUNK 49   // ceil(50000/1024)

// ---------------- CSR build ----------------

__global__ __launch_bounds__(256)
void k_count4(const int* __restrict__ dst, int* __restrict__ cnt) {
    int i = blockIdx.x * 256 + threadIdx.x;
    if (i < N_EDGES / 4) {
        int4 d = ((const int4*)dst)[i];
        atomicAdd(&cnt[d.x], 1);
        atomicAdd(&cnt[d.y], 1);
        atomicAdd(&cnt[d.z], 1);
        atomicAdd(&cnt[d.w], 1);
    }
}

__global__ __launch_bounds__(256)
void k_dis(const int* __restrict__ cnt, float* __restrict__ dis) {
    int i = blockIdx.x * 256 + threadIdx.x;
    if (i < N_NODES) dis[i] = rsqrtf((float)(1 + cnt[i]));  // +1 self loop
}

// xd[n] = dis[n] * x[n]  (one float4 per thread)
__global__ __launch_bounds__(256)
void k_prescale(const float* __restrict__ x, const float* __restrict__ dis,
                float* __restrict__ xd) {
    int i = blockIdx.x * 256 + threadIdx.x;
    if (i < N_NODES * (NF / 4)) {
        float d = dis[i >> 5];
        float4 v = ((const float4*)x)[i];
        v.x *= d; v.y *= d; v.z *= d; v.w *= d;
        ((float4*)xd)[i] = v;
    }
}

// exclusive scan of cnt -> row_start; primes cursor. cnt may alias cursor
// (each element is read before its cursor slot is written, same thread).
__global__ __launch_bounds__(SCAN_T)
void k_scan(const int* __restrict__ cnt, int* __restrict__ row_start,
            int* __restrict__ cursor) {
    __shared__ int ps[SCAN_T];
    const int t = threadIdx.x;
    const int base = t * CHUNK;
    int s = 0;
    for (int i = 0; i < CHUNK; i++) {
        int idx = base + i;
        if (idx < N_NODES) s += cnt[idx];
    }
    ps[t] = s;
    __syncthreads();
    const int my = s;
    for (int off = 1; off < SCAN_T; off <<= 1) {
        int v = (t >= off) ? ps[t - off] : 0;
        __syncthreads();
        ps[t] += v;
        __syncthreads();
    }
    int run = ps[t] - my;
    for (int i = 0; i < CHUNK; i++) {
        int idx = base + i;
        if (idx < N_NODES) {
            int c = cnt[idx];
            row_start[idx] = run;
            cursor[idx] = run;
            run += c;
        }
    }
    if (t == SCAN_T - 1) row_start[N_NODES] = ps[t];
}

__global__ __launch_bounds__(256)
void k_fill4(const int* __restrict__ src, const int* __restrict__ dst,
             int* __restrict__ cursor, int* __restrict__ csr_src) {
    int i = blockIdx.x * 256 + threadIdx.x;
    if (i < N_EDGES / 4) {
        int4 s = ((const int4*)src)[i];
        int4 d = ((const int4*)dst)[i];
        csr_src[atomicAdd(&cursor[d.x], 1)] = s.x;
        csr_src[atomicAdd(&cursor[d.y], 1)] = s.y;
        csr_src[atomicAdd(&cursor[d.z], 1)] = s.z;
        csr_src[atomicAdd(&cursor[d.w], 1)] = s.w;
    }
}

// ---------------- fused gather + GEMM ----------------
// featd is PRE-SCALED (dis[s]*feat[s]); agg[n] = dis[n] * (xd[n] + sum xd[s]).
// Gather: wave w owns 8 nodes; 32-lane halves take contiguous csr ranges,
// 4-way unrolled (4 independent float4 loads in flight). lane&31 owns one
// float4 of the 128 feats.
// MODE 1: C = dis[row] * (relu(acc+b) + skip)   (writes pre-scaled h2s)
// MODE 0: C = acc + b

template <int MODE>
__global__ __launch_bounds__(512)
void k_fused(const int* __restrict__ row_start, const int* __restrict__ csr_src,
             const float* __restrict__ dis, const float* __restrict__ featd,
             const float* __restrict__ W, const float* __restrict__ bias,
             const float* __restrict__ skip, float* __restrict__ C) {
    __shared__ float xs[64 * 132];
    const int t = threadIdx.x;
    const int row0 = blockIdx.x * 64;
    const float4* f4 = (const float4*)featd;

    {   // ---- gather phase ----
        const int wave = t >> 6;
        const int lane = t & 63;
        const int half = lane >> 5;
        const int hl = lane & 31;
        for (int i = 0; i < 8; i++) {
            const int r = wave * 8 + i;
            const int n = row0 + r;
            float4 a = make_float4(0.f, 0.f, 0.f, 0.f);
            if (n < N_NODES) {
                const int st = row_start[n], en = row_start[n + 1];
                const int hh = (en - st + 1) >> 1;
                int j        = half ? st + hh : st;
                const int je = half ? en : st + hh;
                if (half == 0) a = f4[(size_t)n * 32 + hl];   // self loop
                for (; j + 3 < je; j += 4) {
                    int s0 = csr_src[j], s1 = csr_src[j + 1];
                    int s2 = csr_src[j + 2], s3 = csr_src[j + 3];
                    float4 f0 = f4[(size_t)s0 * 32 + hl];
                    float4 f1 = f4[(size_t)s1 * 32 + hl];
                    float4 f2 = f4[(size_t)s2 * 32 + hl];
                    float4 f3 = f4[(size_t)s3 * 32 + hl];
                    a.x += (f0.x + f1.x) + (f2.x + f3.x);
                    a.y += (f0.y + f1.y) + (f2.y + f3.y);
                    a.z += (f0.z + f1.z) + (f2.z + f3.z);
                    a.w += (f0.w + f1.w) + (f2.w + f3.w);
                }
                for (; j < je; ++j) {
                    float4 f = f4[(size_t)csr_src[j] * 32 + hl];
                    a.x += f.x; a.y += f.y; a.z += f.z; a.w += f.w;
                }
            }
            a.x += __shfl_down(a.x, 32);
            a.y += __shfl_down(a.y, 32);
            a.z += __shfl_down(a.z, 32);
            a.w += __shfl_down(a.w, 32);
            if (half == 0) {
                const float dn = (n < N_NODES) ? dis[n] : 0.f;
                a.x *= dn; a.y *= dn; a.z *= dn; a.w *= dn;
                *(float4*)(xs + r * 132 + hl * 4) = a;
            }
        }
    }
    __syncthreads();

    // ---- GEMM phase: tx->4 cols, ty->4 rows ----
    const int tx = t & 31, ty = t >> 5;
    const int col = tx * 4;
    float acc[4][4];
#pragma unroll
    for (int r = 0; r < 4; r++)
#pragma unroll
        for (int j = 0; j < 4; j++) acc[r][j] = 0.f;

#pragma unroll 8
    for (int k0 = 0; k0 < 128; k0 += 4) {
        float4 w0 = *(const float4*)(W + (size_t)(k0 + 0) * NF + col);
        float4 w1 = *(const float4*)(W + (size_t)(k0 + 1) * NF + col);
        float4 w2 = *(const float4*)(W + (size_t)(k0 + 2) * NF + col);
        float4 w3 = *(const float4*)(W + (size_t)(k0 + 3) * NF + col);
#pragma unroll
        for (int r = 0; r < 4; r++) {
            float4 a = *(const float4*)(xs + (ty * 4 + r) * 132 + k0);
            acc[r][0] += a.x * w0.x + a.y * w1.x + a.z * w2.x + a.w * w3.x;
            acc[r][1] += a.x * w0.y + a.y * w1.y + a.z * w2.y + a.w * w3.y;
            acc[r][2] += a.x * w0.z + a.y * w1.z + a.z * w2.z + a.w * w3.z;
            acc[r][3] += a.x * w0.w + a.y * w1.w + a.z * w2.w + a.w * w3.w;
        }
    }

    float4 b = *(const float4*)(bias + col);
#pragma unroll
    for (int r = 0; r < 4; r++) {
        int row = row0 + ty * 4 + r;
        if (row < N_NODES) {
            float4 o;
            o.x = acc[r][0] + b.x;
            o.y = acc[r][1] + b.y;
            o.z = acc[r][2] + b.z;
            o.w = acc[r][3] + b.w;
            if (MODE == 1) {
                float4 s4 = *(const float4*)(skip + (size_t)row * NF + col);
                float dn = dis[row];
                o.x = dn * (fmaxf(o.x, 0.f) + s4.x);
                o.y = dn * (fmaxf(o.y, 0.f) + s4.y);
                o.z = dn * (fmaxf(o.z, 0.f) + s4.z);
                o.w = dn * (fmaxf(o.w, 0.f) + s4.w);
            }
            *(float4*)(C + (size_t)row * NF + col) = o;
        }
    }
}

// ---------------- launch ----------------

extern "C" void kernel_launch(void* const* d_in, const int* in_sizes, int n_in,
                              void* d_out, int out_size, void* d_ws, size_t ws_size,
                              hipStream_t stream) {
    const int*   ei = (const int*)d_in[0];
    const float* x  = (const float*)d_in[1];
    const float* W1 = (const float*)d_in[2];
    const float* b1 = (const float*)d_in[3];
    const float* W2 = (const float*)d_in[4];
    const float* b2 = (const float*)d_in[5];
    float* out = (float*)d_out;

    const int* src = ei;             // edge_index[0]
    const int* dst = ei + N_EDGES;   // edge_index[1]

    // workspace layout
    char* w = (char*)d_ws;
    float* dis       = (float*)(w);                    // [N]
    int*   row_start = (int*)  (w + 200192);           // [N+1]
    int*   cursor    = (int*)  (w + 400640);           // [N] (also cnt)
    int*   csr_src   = (int*)  (w + 600832);           // [E] 3.2 MB
    float* h2s       = (float*)(w + 3801088);          // [N*128] 25.6 MB
    float* xd        = out;                            // d_out doubles as scratch

    const int e4blk = (N_EDGES / 4 + 255) / 256;
    const int nblk  = (N_NODES + 255) / 256;
    const int pblk  = (N_NODES * (NF / 4) + 255) / 256;
    const int fblk  = (N_NODES + 63) / 64;

    // CSR build + prescale
    hipMemsetAsync(cursor, 0, N_NODES * sizeof(int), stream);    // cnt = 0
    k_count4<<<e4blk, 256, 0, stream>>>(dst, cursor);
    k_dis<<<nblk, 256, 0, stream>>>(cursor, dis);
    k_prescale<<<pblk, 256, 0, stream>>>(x, dis, xd);
    k_scan<<<1, SCAN_T, 0, stream>>>(cursor, row_start, cursor);
    k_fill4<<<e4blk, 256, 0, stream>>>(src, dst, cursor, csr_src);

    // layer 1: h2s = dis * (relu(gather(xd)@W1 + b1) + x)
    k_fused<1><<<fblk, 512, 0, stream>>>(row_start, csr_src, dis, xd, W1, b1, x, h2s);
    // layer 2: out = gather(h2s)@W2 + b2
    k_fused<0><<<fblk, 512, 0, stream>>>(row_start, csr_src, dis, h2s, W2, b2, nullptr, out);
}

// Round 8
// 315.602 us; speedup vs baseline: 9.4940x; 1.3953x over previous
//
#include <hip/hip_runtime.h>

#define N_NODES 50000
#define N_EDGES 800000
#define NF 128
#define N4 (N_NODES / 4)          // 12500 int4 groups (N_NODES % 4 == 0)
#define SCAN_BLKS ((N4 + 255) / 256)   // 49

// ---------------- CSR build ----------------

__global__ __launch_bounds__(256)
void k_count4(const int* __restrict__ dst, int* __restrict__ cnt) {
    int i = blockIdx.x * 256 + threadIdx.x;
    if (i < N_EDGES / 4) {
        int4 d = ((const int4*)dst)[i];
        atomicAdd(&cnt[d.x], 1);
        atomicAdd(&cnt[d.y], 1);
        atomicAdd(&cnt[d.z], 1);
        atomicAdd(&cnt[d.w], 1);
    }
}

// phase A: per-block (1024-elem) sums of cnt
__global__ __launch_bounds__(256)
void k_blksum(const int* __restrict__ cnt, int* __restrict__ blksum) {
    __shared__ int ls[256];
    const int t = threadIdx.x;
    int gi = blockIdx.x * 256 + t;           // int4 index
    int s = 0;
    if (gi < N4) {
        int4 c = ((const int4*)cnt)[gi];
        s = c.x + c.y + c.z + c.w;
    }
    ls[t] = s;
    __syncthreads();
    for (int off = 128; off > 0; off >>= 1) {
        if (t < off) ls[t] += ls[t + off];
        __syncthreads();
    }
    if (t == 0) blksum[blockIdx.x] = ls[0];
}

// phase B: exclusive scan of SCAN_BLKS block sums (fits one 64-thread block)
__global__ __launch_bounds__(64)
void k_scanblk(const int* __restrict__ blksum, int* __restrict__ blkoff) {
    __shared__ int ps[64];
    const int t = threadIdx.x;
    int v = (t < SCAN_BLKS) ? blksum[t] : 0;
    ps[t] = v;
    __syncthreads();
    const int my = v;
    for (int off = 1; off < 64; off <<= 1) {
        int u = (t >= off) ? ps[t - off] : 0;
        __syncthreads();
        ps[t] += u;
        __syncthreads();
    }
    if (t < SCAN_BLKS) blkoff[t] = ps[t] - my;
}

// phase C: block-level exclusive scan + offset -> row_start & cursor (int4),
// plus dis = rsqrt(1+cnt) folded in. cnt may alias cursor: each int4 slot is
// read before written by the same thread (no __restrict__ on those args).
__global__ __launch_bounds__(256)
void k_scan_c(const int* cnt, const int* __restrict__ blkoff,
              int* __restrict__ row_start, int* cursor, float* __restrict__ dis) {
    __shared__ int ps[256];
    const int t = threadIdx.x;
    const int b = blockIdx.x;
    const int gi = b * 256 + t;              // int4 index
    int4 c = make_int4(0, 0, 0, 0);
    if (gi < N4) c = ((const int4*)cnt)[gi];
    int s = c.x + c.y + c.z + c.w;
    ps[t] = s;
    __syncthreads();
    const int my = s;
    for (int off = 1; off < 256; off <<= 1) {
        int u = (t >= off) ? ps[t - off] : 0;
        __syncthreads();
        ps[t] += u;
        __syncthreads();
    }
    if (gi < N4) {
        int r0 = ps[t] - my + blkoff[b];
        int r1 = r0 + c.x, r2 = r1 + c.y, r3 = r2 + c.z;
        int4 r = make_int4(r0, r1, r2, r3);
        ((int4*)row_start)[gi] = r;
        ((int4*)cursor)[gi] = r;
        ((float4*)dis)[gi] = make_float4(
            rsqrtf((float)(1 + c.x)), rsqrtf((float)(1 + c.y)),
            rsqrtf((float)(1 + c.z)), rsqrtf((float)(1 + c.w)));
    }
    if (b == 0 && t == 0) row_start[N_NODES] = N_EDGES;
}

// xd[n] = dis[n] * x[n]  (one float4 per thread)
__global__ __launch_bounds__(256)
void k_prescale(const float* __restrict__ x, const float* __restrict__ dis,
                float* __restrict__ xd) {
    int i = blockIdx.x * 256 + threadIdx.x;
    if (i < N_NODES * (NF / 4)) {
        float d = dis[i >> 5];
        float4 v = ((const float4*)x)[i];
        v.x *= d; v.y *= d; v.z *= d; v.w *= d;
        ((float4*)xd)[i] = v;
    }
}

__global__ __launch_bounds__(256)
void k_fill4(const int* __restrict__ src, const int* __restrict__ dst,
             int* __restrict__ cursor, int* __restrict__ csr_src) {
    int i = blockIdx.x * 256 + threadIdx.x;
    if (i < N_EDGES / 4) {
        int4 s = ((const int4*)src)[i];
        int4 d = ((const int4*)dst)[i];
        csr_src[atomicAdd(&cursor[d.x], 1)] = s.x;
        csr_src[atomicAdd(&cursor[d.y], 1)] = s.y;
        csr_src[atomicAdd(&cursor[d.z], 1)] = s.z;
        csr_src[atomicAdd(&cursor[d.w], 1)] = s.w;
    }
}

// ---------------- fused gather + GEMM ----------------
// featd is PRE-SCALED (dis[s]*feat[s]); agg[n] = dis[n] * (xd[n] + sum xd[s]).
// Gather: wave w owns 8 nodes; 32-lane halves take contiguous csr ranges,
// 4-way unrolled. lane&31 owns one float4 of the 128 feats.
// MODE 1: C = dis[row] * (relu(acc+b) + skip)   (writes pre-scaled h2s)
// MODE 0: C = acc + b

template <int MODE>
__global__ __launch_bounds__(512)
void k_fused(const int* __restrict__ row_start, const int* __restrict__ csr_src,
             const float* __restrict__ dis, const float* __restrict__ featd,
             const float* __restrict__ W, const float* __restrict__ bias,
             const float* __restrict__ skip, float* __restrict__ C) {
    __shared__ float xs[64 * 132];
    const int t = threadIdx.x;
    const int row0 = blockIdx.x * 64;
    const float4* f4 = (const float4*)featd;

    {   // ---- gather phase ----
        const int wave = t >> 6;
        const int lane = t & 63;
        const int half = lane >> 5;
        const int hl = lane & 31;
        for (int i = 0; i < 8; i++) {
            const int r = wave * 8 + i;
            const int n = row0 + r;
            float4 a = make_float4(0.f, 0.f, 0.f, 0.f);
            if (n < N_NODES) {
                const int st = row_start[n], en = row_start[n + 1];
                const int hh = (en - st + 1) >> 1;
                int j        = half ? st + hh : st;
                const int je = half ? en : st + hh;
                if (half == 0) a = f4[(size_t)n * 32 + hl];   // self loop
                for (; j + 3 < je; j += 4) {
                    int s0 = csr_src[j], s1 = csr_src[j + 1];
                    int s2 = csr_src[j + 2], s3 = csr_src[j + 3];
                    float4 f0 = f4[(size_t)s0 * 32 + hl];
                    float4 f1 = f4[(size_t)s1 * 32 + hl];
                    float4 f2 = f4[(size_t)s2 * 32 + hl];
                    float4 f3 = f4[(size_t)s3 * 32 + hl];
                    a.x += (f0.x + f1.x) + (f2.x + f3.x);
                    a.y += (f0.y + f1.y) + (f2.y + f3.y);
                    a.z += (f0.z + f1.z) + (f2.z + f3.z);
                    a.w += (f0.w + f1.w) + (f2.w + f3.w);
                }
                for (; j < je; ++j) {
                    float4 f = f4[(size_t)csr_src[j] * 32 + hl];
                    a.x += f.x; a.y += f.y; a.z += f.z; a.w += f.w;
                }
            }
            a.x += __shfl_down(a.x, 32);
            a.y += __shfl_down(a.y, 32);
            a.z += __shfl_down(a.z, 32);
            a.w += __shfl_down(a.w, 32);
            if (half == 0) {
                const float dn = (n < N_NODES) ? dis[n] : 0.f;
                a.x *= dn; a.y *= dn; a.z *= dn; a.w *= dn;
                *(float4*)(xs + r * 132 + hl * 4) = a;
            }
        }
    }
    __syncthreads();

    // ---- GEMM phase: tx->4 cols, ty->4 rows ----
    const int tx = t & 31, ty = t >> 5;
    const int col = tx * 4;
    float acc[4][4];
#pragma unroll
    for (int r = 0; r < 4; r++)
#pragma unroll
        for (int j = 0; j < 4; j++) acc[r][j] = 0.f;

#pragma unroll 8
    for (int k0 = 0; k0 < 128; k0 += 4) {
        float4 w0 = *(const float4*)(W + (size_t)(k0 + 0) * NF + col);
        float4 w1 = *(const float4*)(W + (size_t)(k0 + 1) * NF + col);
        float4 w2 = *(const float4*)(W + (size_t)(k0 + 2) * NF + col);
        float4 w3 = *(const float4*)(W + (size_t)(k0 + 3) * NF + col);
#pragma unroll
        for (int r = 0; r < 4; r++) {
            float4 a = *(const float4*)(xs + (ty * 4 + r) * 132 + k0);
            acc[r][0] += a.x * w0.x + a.y * w1.x + a.z * w2.x + a.w * w3.x;
            acc[r][1] += a.x * w0.y + a.y * w1.y + a.z * w2.y + a.w * w3.y;
            acc[r][2] += a.x * w0.z + a.y * w1.z + a.z * w2.z + a.w * w3.z;
            acc[r][3] += a.x * w0.w + a.y * w1.w + a.z * w2.w + a.w * w3.w;
        }
    }

    float4 b = *(const float4*)(bias + col);
#pragma unroll
    for (int r = 0; r < 4; r++) {
        int row = row0 + ty * 4 + r;
        if (row < N_NODES) {
            float4 o;
            o.x = acc[r][0] + b.x;
            o.y = acc[r][1] + b.y;
            o.z = acc[r][2] + b.z;
            o.w = acc[r][3] + b.w;
            if (MODE == 1) {
                float4 s4 = *(const float4*)(skip + (size_t)row * NF + col);
                float dn = dis[row];
                o.x = dn * (fmaxf(o.x, 0.f) + s4.x);
                o.y = dn * (fmaxf(o.y, 0.f) + s4.y);
                o.z = dn * (fmaxf(o.z, 0.f) + s4.z);
                o.w = dn * (fmaxf(o.w, 0.f) + s4.w);
            }
            *(float4*)(C + (size_t)row * NF + col) = o;
        }
    }
}

// ---------------- launch ----------------

extern "C" void kernel_launch(void* const* d_in, const int* in_sizes, int n_in,
                              void* d_out, int out_size, void* d_ws, size_t ws_size,
                              hipStream_t stream) {
    const int*   ei = (const int*)d_in[0];
    const float* x  = (const float*)d_in[1];
    const float* W1 = (const float*)d_in[2];
    const float* b1 = (const float*)d_in[3];
    const float* W2 = (const float*)d_in[4];
    const float* b2 = (const float*)d_in[5];
    float* out = (float*)d_out;

    const int* src = ei;             // edge_index[0]
    const int* dst = ei + N_EDGES;   // edge_index[1]

    // workspace layout (unchanged footprint ~29.4 MB)
    char* w = (char*)d_ws;
    float* dis       = (float*)(w);                    // [N]
    int*   row_start = (int*)  (w + 200192);           // [N+1]
    int*   cursor    = (int*)  (w + 400640);           // [N] (cnt aliases this)
    int*   csr_src   = (int*)  (w + 600832);           // [E] 3.2 MB
    float* h2s       = (float*)(w + 3801088);          // [N*128] 25.6 MB
    int*   blk       = (int*)  (w + 29427712);         // [64+64] blksum/blkoff
    float* xd        = out;                            // d_out doubles as scratch
    int*   cnt       = cursor;

    const int e4blk = (N_EDGES / 4 + 255) / 256;
    const int pblk  = (N_NODES * (NF / 4) + 255) / 256;
    const int fblk  = (N_NODES + 63) / 64;

    // CSR build + dis + prescale
    hipMemsetAsync(cnt, 0, N_NODES * sizeof(int), stream);
    k_count4<<<e4blk, 256, 0, stream>>>(dst, cnt);
    k_blksum<<<SCAN_BLKS, 256, 0, stream>>>(cnt, blk);
    k_scanblk<<<1, 64, 0, stream>>>(blk, blk + 64);
    k_scan_c<<<SCAN_BLKS, 256, 0, stream>>>(cnt, blk + 64, row_start, cursor, dis);
    k_prescale<<<pblk, 256, 0, stream>>>(x, dis, xd);
    k_fill4<<<e4blk, 256, 0, stream>>>(src, dst, cursor, csr_src);

    // layer 1: h2s = dis * (relu(gather(xd)@W1 + b1) + x)
    k_fused<1><<<fblk, 512, 0, stream>>>(row_start, csr_src, dis, xd, W1, b1, x, h2s);
    // layer 2: out = gather(h2s)@W2 + b2
    k_fused<0><<<fblk, 512, 0, stream>>>(row_start, csr_src, dis, h2s, W2, b2, nullptr, out);
}

// Round 9
// 298.956 us; speedup vs baseline: 10.0226x; 1.0557x over previous
//
#include <hip/hip_runtime.h>
#include <hip/hip_fp16.h>

#define N_NODES 50000
#define N_EDGES 800000
#define NF 128
#define N4 (N_NODES / 4)
#define SCAN_BLKS ((N4 + 255) / 256)   // 49

// ---------------- CSR build ----------------

__global__ __launch_bounds__(256)
void k_count4(const int* __restrict__ dst, int* __restrict__ cnt) {
    int i = blockIdx.x * 256 + threadIdx.x;
    if (i < N_EDGES / 4) {
        int4 d = ((const int4*)dst)[i];
        atomicAdd(&cnt[d.x], 1);
        atomicAdd(&cnt[d.y], 1);
        atomicAdd(&cnt[d.z], 1);
        atomicAdd(&cnt[d.w], 1);
    }
}

__global__ __launch_bounds__(256)
void k_blksum(const int* __restrict__ cnt, int* __restrict__ blksum) {
    __shared__ int ls[256];
    const int t = threadIdx.x;
    int gi = blockIdx.x * 256 + t;           // int4 index
    int s = 0;
    if (gi < N4) {
        int4 c = ((const int4*)cnt)[gi];
        s = c.x + c.y + c.z + c.w;
    }
    ls[t] = s;
    __syncthreads();
    for (int off = 128; off > 0; off >>= 1) {
        if (t < off) ls[t] += ls[t + off];
        __syncthreads();
    }
    if (t == 0) blksum[blockIdx.x] = ls[0];
}

__global__ __launch_bounds__(64)
void k_scanblk(const int* __restrict__ blksum, int* __restrict__ blkoff) {
    __shared__ int ps[64];
    const int t = threadIdx.x;
    int v = (t < SCAN_BLKS) ? blksum[t] : 0;
    ps[t] = v;
    __syncthreads();
    const int my = v;
    for (int off = 1; off < 64; off <<= 1) {
        int u = (t >= off) ? ps[t - off] : 0;
        __syncthreads();
        ps[t] += u;
        __syncthreads();
    }
    if (t < SCAN_BLKS) blkoff[t] = ps[t] - my;
}

// phase C: exclusive scan + offset -> row_start & cursor (int4), dis folded in.
// cnt aliases cursor (each slot read before written by same thread).
__global__ __launch_bounds__(256)
void k_scan_c(const int* cnt, const int* __restrict__ blkoff,
              int* __restrict__ row_start, int* cursor, float* __restrict__ dis) {
    __shared__ int ps[256];
    const int t = threadIdx.x;
    const int b = blockIdx.x;
    const int gi = b * 256 + t;
    int4 c = make_int4(0, 0, 0, 0);
    if (gi < N4) c = ((const int4*)cnt)[gi];
    int s = c.x + c.y + c.z + c.w;
    ps[t] = s;
    __syncthreads();
    const int my = s;
    for (int off = 1; off < 256; off <<= 1) {
        int u = (t >= off) ? ps[t - off] : 0;
        __syncthreads();
        ps[t] += u;
        __syncthreads();
    }
    if (gi < N4) {
        int r0 = ps[t] - my + blkoff[b];
        int r1 = r0 + c.x, r2 = r1 + c.y, r3 = r2 + c.z;
        int4 r = make_int4(r0, r1, r2, r3);
        ((int4*)row_start)[gi] = r;
        ((int4*)cursor)[gi] = r;
        ((float4*)dis)[gi] = make_float4(
            rsqrtf((float)(1 + c.x)), rsqrtf((float)(1 + c.y)),
            rsqrtf((float)(1 + c.z)), rsqrtf((float)(1 + c.w)));
    }
    if (b == 0 && t == 0) row_start[N_NODES] = N_EDGES;
}

// xd16[n] = fp16(dis[n] * x[n])  — one float4 -> 4 halves per thread
__global__ __launch_bounds__(256)
void k_prescale16(const float* __restrict__ x, const float* __restrict__ dis,
                  __half* __restrict__ xd) {
    int i = blockIdx.x * 256 + threadIdx.x;
    if (i < N_NODES * (NF / 4)) {
        float d = dis[i >> 5];
        float4 v = ((const float4*)x)[i];
        union { __half2 h[2]; uint2 u; } pk;
        pk.h[0] = __floats2half2_rn(d * v.x, d * v.y);
        pk.h[1] = __floats2half2_rn(d * v.z, d * v.w);
        ((uint2*)xd)[i] = pk.u;
    }
}

__global__ __launch_bounds__(256)
void k_fill4(const int* __restrict__ src, const int* __restrict__ dst,
             int* __restrict__ cursor, int* __restrict__ csr_src) {
    int i = blockIdx.x * 256 + threadIdx.x;
    if (i < N_EDGES / 4) {
        int4 s = ((const int4*)src)[i];
        int4 d = ((const int4*)dst)[i];
        csr_src[atomicAdd(&cursor[d.x], 1)] = s.x;
        csr_src[atomicAdd(&cursor[d.y], 1)] = s.y;
        csr_src[atomicAdd(&cursor[d.z], 1)] = s.z;
        csr_src[atomicAdd(&cursor[d.w], 1)] = s.w;
    }
}

// ---------------- fused gather(fp16) + GEMM(fp32) ----------------
// featd: PRE-SCALED fp16 rows (dis[s]*feat[s]); agg[n]=dis[n]*(featd[n]+sum featd[s]).
// Lane hl owns 4 feats = one uint2 (8B) of the 256B fp16 row.
// MODE 1: h2s16 = fp16( dis[row] * (relu(acc+b) + skip_f32) )
// MODE 0: C_f32 = acc + b

__device__ inline float4 ld16(const uint2* __restrict__ f2, size_t idx) {
    uint2 u = f2[idx];
    __half2 h0 = __builtin_bit_cast(__half2, u.x);
    __half2 h1 = __builtin_bit_cast(__half2, u.y);
    float2 a = __half22float2(h0);
    float2 b = __half22float2(h1);
    return make_float4(a.x, a.y, b.x, b.y);
}

template <int MODE>
__global__ __launch_bounds__(512)
void k_fused(const int* __restrict__ row_start, const int* __restrict__ csr_src,
             const float* __restrict__ dis, const __half* __restrict__ featd,
             const float* __restrict__ W, const float* __restrict__ bias,
             const float* __restrict__ skip, void* __restrict__ C) {
    __shared__ float xs[64 * 132];
    const int t = threadIdx.x;
    const int row0 = blockIdx.x * 64;
    const uint2* f2 = (const uint2*)featd;   // row stride = 32 uint2

    {   // ---- gather phase ----
        const int wave = t >> 6;
        const int lane = t & 63;
        const int half = lane >> 5;
        const int hl = lane & 31;
        for (int i = 0; i < 8; i++) {
            const int r = wave * 8 + i;
            const int n = row0 + r;
            float4 a = make_float4(0.f, 0.f, 0.f, 0.f);
            if (n < N_NODES) {
                const int st = row_start[n], en = row_start[n + 1];
                const int hh = (en - st + 1) >> 1;
                int j        = half ? st + hh : st;
                const int je = half ? en : st + hh;
                if (half == 0) a = ld16(f2, (size_t)n * 32 + hl);  // self loop
                for (; j + 3 < je; j += 4) {
                    int s0 = csr_src[j], s1 = csr_src[j + 1];
                    int s2 = csr_src[j + 2], s3 = csr_src[j + 3];
                    float4 f0 = ld16(f2, (size_t)s0 * 32 + hl);
                    float4 f1 = ld16(f2, (size_t)s1 * 32 + hl);
                    float4 f2v = ld16(f2, (size_t)s2 * 32 + hl);
                    float4 f3 = ld16(f2, (size_t)s3 * 32 + hl);
                    a.x += (f0.x + f1.x) + (f2v.x + f3.x);
                    a.y += (f0.y + f1.y) + (f2v.y + f3.y);
                    a.z += (f0.z + f1.z) + (f2v.z + f3.z);
                    a.w += (f0.w + f1.w) + (f2v.w + f3.w);
                }
                for (; j < je; ++j) {
                    float4 f = ld16(f2, (size_t)csr_src[j] * 32 + hl);
                    a.x += f.x; a.y += f.y; a.z += f.z; a.w += f.w;
                }
            }
            a.x += __shfl_down(a.x, 32);
            a.y += __shfl_down(a.y, 32);
            a.z += __shfl_down(a.z, 32);
            a.w += __shfl_down(a.w, 32);
            if (half == 0) {
                const float dn = (n < N_NODES) ? dis[n] : 0.f;
                a.x *= dn; a.y *= dn; a.z *= dn; a.w *= dn;
                *(float4*)(xs + r * 132 + hl * 4) = a;
            }
        }
    }
    __syncthreads();

    // ---- GEMM phase: tx->4 cols, ty->4 rows ----
    const int tx = t & 31, ty = t >> 5;
    const int col = tx * 4;
    float acc[4][4];
#pragma unroll
    for (int r = 0; r < 4; r++)
#pragma unroll
        for (int j = 0; j < 4; j++) acc[r][j] = 0.f;

#pragma unroll 8
    for (int k0 = 0; k0 < 128; k0 += 4) {
        float4 w0 = *(const float4*)(W + (size_t)(k0 + 0) * NF + col);
        float4 w1 = *(const float4*)(W + (size_t)(k0 + 1) * NF + col);
        float4 w2 = *(const float4*)(W + (size_t)(k0 + 2) * NF + col);
        float4 w3 = *(const float4*)(W + (size_t)(k0 + 3) * NF + col);
#pragma unroll
        for (int r = 0; r < 4; r++) {
            float4 a = *(const float4*)(xs + (ty * 4 + r) * 132 + k0);
            acc[r][0] += a.x * w0.x + a.y * w1.x + a.z * w2.x + a.w * w3.x;
            acc[r][1] += a.x * w0.y + a.y * w1.y + a.z * w2.y + a.w * w3.y;
            acc[r][2] += a.x * w0.z + a.y * w1.z + a.z * w2.z + a.w * w3.z;
            acc[r][3] += a.x * w0.w + a.y * w1.w + a.z * w2.w + a.w * w3.w;
        }
    }

    float4 b = *(const float4*)(bias + col);
#pragma unroll
    for (int r = 0; r < 4; r++) {
        int row = row0 + ty * 4 + r;
        if (row < N_NODES) {
            float4 o;
            o.x = acc[r][0] + b.x;
            o.y = acc[r][1] + b.y;
            o.z = acc[r][2] + b.z;
            o.w = acc[r][3] + b.w;
            if (MODE == 1) {
                float4 s4 = *(const float4*)(skip + (size_t)row * NF + col);
                float dn = dis[row];
                o.x = dn * (fmaxf(o.x, 0.f) + s4.x);
                o.y = dn * (fmaxf(o.y, 0.f) + s4.y);
                o.z = dn * (fmaxf(o.z, 0.f) + s4.z);
                o.w = dn * (fmaxf(o.w, 0.f) + s4.w);
                union { __half2 h[2]; uint2 u; } pk;
                pk.h[0] = __floats2half2_rn(o.x, o.y);
                pk.h[1] = __floats2half2_rn(o.z, o.w);
                *(uint2*)((__half*)C + (size_t)row * NF + col) = pk.u;
            } else {
                *(float4*)((float*)C + (size_t)row * NF + col) = o;
            }
        }
    }
}

// ---------------- launch ----------------

extern "C" void kernel_launch(void* const* d_in, const int* in_sizes, int n_in,
                              void* d_out, int out_size, void* d_ws, size_t ws_size,
                              hipStream_t stream) {
    const int*   ei = (const int*)d_in[0];
    const float* x  = (const float*)d_in[1];
    const float* W1 = (const float*)d_in[2];
    const float* b1 = (const float*)d_in[3];
    const float* W2 = (const float*)d_in[4];
    const float* b2 = (const float*)d_in[5];
    float* out = (float*)d_out;

    const int* src = ei;             // edge_index[0]
    const int* dst = ei + N_EDGES;   // edge_index[1]

    // workspace layout
    char* w = (char*)d_ws;
    float*  dis       = (float*)(w);                    // [N]
    int*    row_start = (int*)  (w + 200192);           // [N+1]
    int*    cursor    = (int*)  (w + 400640);           // [N] (cnt aliases)
    int*    csr_src   = (int*)  (w + 600832);           // [E] 3.2 MB
    __half* h2s       = (__half*)(w + 3801088);         // [N*128] fp16 12.8 MB
    int*    blk       = (int*)  (w + 29427712);         // [64+64] blksum/blkoff
    __half* xd        = (__half*)out;                   // d_out as fp16 scratch
    int*    cnt       = cursor;

    const int e4blk = (N_EDGES / 4 + 255) / 256;
    const int pblk  = (N_NODES * (NF / 4) + 255) / 256;
    const int fblk  = (N_NODES + 63) / 64;

    // CSR build + dis + prescale(fp16)
    hipMemsetAsync(cnt, 0, N_NODES * sizeof(int), stream);
    k_count4<<<e4blk, 256, 0, stream>>>(dst, cnt);
    k_blksum<<<SCAN_BLKS, 256, 0, stream>>>(cnt, blk);
    k_scanblk<<<1, 64, 0, stream>>>(blk, blk + 64);
    k_scan_c<<<SCAN_BLKS, 256, 0, stream>>>(cnt, blk + 64, row_start, cursor, dis);
    k_prescale16<<<pblk, 256, 0, stream>>>(x, dis, xd);
    k_fill4<<<e4blk, 256, 0, stream>>>(src, dst, cursor, csr_src);

    // layer 1: h2s = fp16(dis * (relu(gather(xd)@W1 + b1) + x))
    k_fused<1><<<fblk, 512, 0, stream>>>(row_start, csr_src, dis, xd, W1, b1, x, h2s);
    // layer 2: out = gather(h2s)@W2 + b2   (fp32 out)
    k_fused<0><<<fblk, 512, 0, stream>>>(row_start, csr_src, dis, h2s, W2, b2, nullptr, out);
}

// Round 10
// 272.945 us; speedup vs baseline: 10.9778x; 1.0953x over previous
//
#include <hip/hip_runtime.h>
#include <hip/hip_fp16.h>

#define N_NODES 50000
#define N_EDGES 800000
#define NF 128
#define N4 (N_NODES / 4)
#define SCAN_BLKS ((N4 + 255) / 256)   // 49
#define TILE 32                         // rows per fused block

// ---------------- CSR build ----------------

__global__ __launch_bounds__(256)
void k_count4(const int* __restrict__ dst, int* __restrict__ cnt) {
    int i = blockIdx.x * 256 + threadIdx.x;
    if (i < N_EDGES / 4) {
        int4 d = ((const int4*)dst)[i];
        atomicAdd(&cnt[d.x], 1);
        atomicAdd(&cnt[d.y], 1);
        atomicAdd(&cnt[d.z], 1);
        atomicAdd(&cnt[d.w], 1);
    }
}

__global__ __launch_bounds__(256)
void k_blksum(const int* __restrict__ cnt, int* __restrict__ blksum) {
    __shared__ int ls[256];
    const int t = threadIdx.x;
    int gi = blockIdx.x * 256 + t;           // int4 index
    int s = 0;
    if (gi < N4) {
        int4 c = ((const int4*)cnt)[gi];
        s = c.x + c.y + c.z + c.w;
    }
    ls[t] = s;
    __syncthreads();
    for (int off = 128; off > 0; off >>= 1) {
        if (t < off) ls[t] += ls[t + off];
        __syncthreads();
    }
    if (t == 0) blksum[blockIdx.x] = ls[0];
}

__global__ __launch_bounds__(64)
void k_scanblk(const int* __restrict__ blksum, int* __restrict__ blkoff) {
    __shared__ int ps[64];
    const int t = threadIdx.x;
    int v = (t < SCAN_BLKS) ? blksum[t] : 0;
    ps[t] = v;
    __syncthreads();
    const int my = v;
    for (int off = 1; off < 64; off <<= 1) {
        int u = (t >= off) ? ps[t - off] : 0;
        __syncthreads();
        ps[t] += u;
        __syncthreads();
    }
    if (t < SCAN_BLKS) blkoff[t] = ps[t] - my;
}

// phase C: exclusive scan + offset -> row_start & cursor (int4), dis folded in.
// cnt aliases cursor (each slot read before written by same thread).
__global__ __launch_bounds__(256)
void k_scan_c(const int* cnt, const int* __restrict__ blkoff,
              int* __restrict__ row_start, int* cursor, float* __restrict__ dis) {
    __shared__ int ps[256];
    const int t = threadIdx.x;
    const int b = blockIdx.x;
    const int gi = b * 256 + t;
    int4 c = make_int4(0, 0, 0, 0);
    if (gi < N4) c = ((const int4*)cnt)[gi];
    int s = c.x + c.y + c.z + c.w;
    ps[t] = s;
    __syncthreads();
    const int my = s;
    for (int off = 1; off < 256; off <<= 1) {
        int u = (t >= off) ? ps[t - off] : 0;
        __syncthreads();
        ps[t] += u;
        __syncthreads();
    }
    if (gi < N4) {
        int r0 = ps[t] - my + blkoff[b];
        int r1 = r0 + c.x, r2 = r1 + c.y, r3 = r2 + c.z;
        int4 r = make_int4(r0, r1, r2, r3);
        ((int4*)row_start)[gi] = r;
        ((int4*)cursor)[gi] = r;
        ((float4*)dis)[gi] = make_float4(
            rsqrtf((float)(1 + c.x)), rsqrtf((float)(1 + c.y)),
            rsqrtf((float)(1 + c.z)), rsqrtf((float)(1 + c.w)));
    }
    if (b == 0 && t == 0) row_start[N_NODES] = N_EDGES;
}

// xd16[n] = fp16(dis[n] * x[n])
__global__ __launch_bounds__(256)
void k_prescale16(const float* __restrict__ x, const float* __restrict__ dis,
                  __half* __restrict__ xd) {
    int i = blockIdx.x * 256 + threadIdx.x;
    if (i < N_NODES * (NF / 4)) {
        float d = dis[i >> 5];
        float4 v = ((const float4*)x)[i];
        union { __half2 h[2]; uint2 u; } pk;
        pk.h[0] = __floats2half2_rn(d * v.x, d * v.y);
        pk.h[1] = __floats2half2_rn(d * v.z, d * v.w);
        ((uint2*)xd)[i] = pk.u;
    }
}

__global__ __launch_bounds__(256)
void k_fill4(const int* __restrict__ src, const int* __restrict__ dst,
             int* __restrict__ cursor, int* __restrict__ csr_src) {
    int i = blockIdx.x * 256 + threadIdx.x;
    if (i < N_EDGES / 4) {
        int4 s = ((const int4*)src)[i];
        int4 d = ((const int4*)dst)[i];
        csr_src[atomicAdd(&cursor[d.x], 1)] = s.x;
        csr_src[atomicAdd(&cursor[d.y], 1)] = s.y;
        csr_src[atomicAdd(&cursor[d.z], 1)] = s.z;
        csr_src[atomicAdd(&cursor[d.w], 1)] = s.w;
    }
}

// ---------------- fused gather(fp16) + GEMM(fp32) ----------------
// TILE=32 rows/block, 256 threads (4 waves; wave owns 8 rows; 32-lane halves
// split each row's edge list; 8-deep unroll -> 8 independent 256B row loads
// in flight per half-wave). lane hl owns one uint2 (4 feats) of the row.
// MODE 1: h2s16 = fp16( dis[row] * (relu(acc+b) + skip_f32) )
// MODE 0: C_f32 = acc + b

__device__ inline float4 ld16(const uint2* __restrict__ f2, size_t idx) {
    uint2 u = f2[idx];
    __half2 h0 = __builtin_bit_cast(__half2, u.x);
    __half2 h1 = __builtin_bit_cast(__half2, u.y);
    float2 a = __half22float2(h0);
    float2 b = __half22float2(h1);
    return make_float4(a.x, a.y, b.x, b.y);
}

#define ACC4(f) do { a.x += f.x; a.y += f.y; a.z += f.z; a.w += f.w; } while (0)

template <int MODE>
__global__ __launch_bounds__(256)
void k_fused(const int* __restrict__ row_start, const int* __restrict__ csr_src,
             const float* __restrict__ dis, const __half* __restrict__ featd,
             const float* __restrict__ W, const float* __restrict__ bias,
             const float* __restrict__ skip, void* __restrict__ C) {
    __shared__ float xs[TILE * 132];
    const int t = threadIdx.x;
    const int row0 = blockIdx.x * TILE;
    const uint2* f2 = (const uint2*)featd;   // row stride = 32 uint2

    {   // ---- gather phase ----
        const int wave = t >> 6;          // 0..3
        const int lane = t & 63;
        const int half = lane >> 5;
        const int hl = lane & 31;
        for (int i = 0; i < 8; i++) {
            const int r = wave * 8 + i;
            const int n = row0 + r;
            float4 a = make_float4(0.f, 0.f, 0.f, 0.f);
            if (n < N_NODES) {
                const int st = row_start[n], en = row_start[n + 1];
                const int hh = (en - st + 1) >> 1;
                int j        = half ? st + hh : st;
                const int je = half ? en : st + hh;
                if (half == 0) a = ld16(f2, (size_t)n * 32 + hl);  // self loop
                for (; j + 7 < je; j += 8) {
                    int s0 = csr_src[j],     s1 = csr_src[j + 1];
                    int s2 = csr_src[j + 2], s3 = csr_src[j + 3];
                    int s4 = csr_src[j + 4], s5 = csr_src[j + 5];
                    int s6 = csr_src[j + 6], s7 = csr_src[j + 7];
                    float4 f0 = ld16(f2, (size_t)s0 * 32 + hl);
                    float4 f1 = ld16(f2, (size_t)s1 * 32 + hl);
                    float4 g2 = ld16(f2, (size_t)s2 * 32 + hl);
                    float4 f3 = ld16(f2, (size_t)s3 * 32 + hl);
                    float4 g4 = ld16(f2, (size_t)s4 * 32 + hl);
                    float4 f5 = ld16(f2, (size_t)s5 * 32 + hl);
                    float4 g6 = ld16(f2, (size_t)s6 * 32 + hl);
                    float4 f7 = ld16(f2, (size_t)s7 * 32 + hl);
                    ACC4(f0); ACC4(f1); ACC4(g2); ACC4(f3);
                    ACC4(g4); ACC4(f5); ACC4(g6); ACC4(f7);
                }
                for (; j + 3 < je; j += 4) {
                    int s0 = csr_src[j],     s1 = csr_src[j + 1];
                    int s2 = csr_src[j + 2], s3 = csr_src[j + 3];
                    float4 f0 = ld16(f2, (size_t)s0 * 32 + hl);
                    float4 f1 = ld16(f2, (size_t)s1 * 32 + hl);
                    float4 g2 = ld16(f2, (size_t)s2 * 32 + hl);
                    float4 f3 = ld16(f2, (size_t)s3 * 32 + hl);
                    ACC4(f0); ACC4(f1); ACC4(g2); ACC4(f3);
                }
                for (; j < je; ++j) {
                    float4 f = ld16(f2, (size_t)csr_src[j] * 32 + hl);
                    ACC4(f);
                }
            }
            a.x += __shfl_down(a.x, 32);
            a.y += __shfl_down(a.y, 32);
            a.z += __shfl_down(a.z, 32);
            a.w += __shfl_down(a.w, 32);
            if (half == 0) {
                const float dn = (n < N_NODES) ? dis[n] : 0.f;
                a.x *= dn; a.y *= dn; a.z *= dn; a.w *= dn;
                *(float4*)(xs + r * 132 + hl * 4) = a;
            }
        }
    }
    __syncthreads();

    // ---- GEMM phase: tx->4 cols, ty(0..7)->4 rows ----
    const int tx = t & 31, ty = t >> 5;
    const int col = tx * 4;
    float acc[4][4];
#pragma unroll
    for (int r = 0; r < 4; r++)
#pragma unroll
        for (int j = 0; j < 4; j++) acc[r][j] = 0.f;

#pragma unroll 8
    for (int k0 = 0; k0 < 128; k0 += 4) {
        float4 w0 = *(const float4*)(W + (size_t)(k0 + 0) * NF + col);
        float4 w1 = *(const float4*)(W + (size_t)(k0 + 1) * NF + col);
        float4 w2 = *(const float4*)(W + (size_t)(k0 + 2) * NF + col);
        float4 w3 = *(const float4*)(W + (size_t)(k0 + 3) * NF + col);
#pragma unroll
        for (int r = 0; r < 4; r++) {
            float4 a = *(const float4*)(xs + (ty * 4 + r) * 132 + k0);
            acc[r][0] += a.x * w0.x + a.y * w1.x + a.z * w2.x + a.w * w3.x;
            acc[r][1] += a.x * w0.y + a.y * w1.y + a.z * w2.y + a.w * w3.y;
            acc[r][2] += a.x * w0.z + a.y * w1.z + a.z * w2.z + a.w * w3.z;
            acc[r][3] += a.x * w0.w + a.y * w1.w + a.z * w2.w + a.w * w3.w;
        }
    }

    float4 b = *(const float4*)(bias + col);
#pragma unroll
    for (int r = 0; r < 4; r++) {
        int row = row0 + ty * 4 + r;
        if (row < N_NODES) {
            float4 o;
            o.x = acc[r][0] + b.x;
            o.y = acc[r][1] + b.y;
            o.z = acc[r][2] + b.z;
            o.w = acc[r][3] + b.w;
            if (MODE == 1) {
                float4 s4 = *(const float4*)(skip + (size_t)row * NF + col);
                float dn = dis[row];
                o.x = dn * (fmaxf(o.x, 0.f) + s4.x);
                o.y = dn * (fmaxf(o.y, 0.f) + s4.y);
                o.z = dn * (fmaxf(o.z, 0.f) + s4.z);
                o.w = dn * (fmaxf(o.w, 0.f) + s4.w);
                union { __half2 h[2]; uint2 u; } pk;
                pk.h[0] = __floats2half2_rn(o.x, o.y);
                pk.h[1] = __floats2half2_rn(o.z, o.w);
                *(uint2*)((__half*)C + (size_t)row * NF + col) = pk.u;
            } else {
                *(float4*)((float*)C + (size_t)row * NF + col) = o;
            }
        }
    }
}

// ---------------- launch ----------------

extern "C" void kernel_launch(void* const* d_in, const int* in_sizes, int n_in,
                              void* d_out, int out_size, void* d_ws, size_t ws_size,
                              hipStream_t stream) {
    const int*   ei = (const int*)d_in[0];
    const float* x  = (const float*)d_in[1];
    const float* W1 = (const float*)d_in[2];
    const float* b1 = (const float*)d_in[3];
    const float* W2 = (const float*)d_in[4];
    const float* b2 = (const float*)d_in[5];
    float* out = (float*)d_out;

    const int* src = ei;             // edge_index[0]
    const int* dst = ei + N_EDGES;   // edge_index[1]

    // workspace layout
    char* w = (char*)d_ws;
    float*  dis       = (float*)(w);                    // [N]
    int*    row_start = (int*)  (w + 200192);           // [N+1]
    int*    cursor    = (int*)  (w + 400640);           // [N] (cnt aliases)
    int*    csr_src   = (int*)  (w + 600832);           // [E] 3.2 MB
    __half* h2s       = (__half*)(w + 3801088);         // [N*128] fp16 12.8 MB
    int*    blk       = (int*)  (w + 29427712);         // [64+64] blksum/blkoff
    __half* xd        = (__half*)out;                   // d_out as fp16 scratch
    int*    cnt       = cursor;

    const int e4blk = (N_EDGES / 4 + 255) / 256;
    const int pblk  = (N_NODES * (NF / 4) + 255) / 256;
    const int fblk  = (N_NODES + TILE - 1) / TILE;

    // CSR build + dis + prescale(fp16)
    hipMemsetAsync(cnt, 0, N_NODES * sizeof(int), stream);
    k_count4<<<e4blk, 256, 0, stream>>>(dst, cnt);
    k_blksum<<<SCAN_BLKS, 256, 0, stream>>>(cnt, blk);
    k_scanblk<<<1, 64, 0, stream>>>(blk, blk + 64);
    k_scan_c<<<SCAN_BLKS, 256, 0, stream>>>(cnt, blk + 64, row_start, cursor, dis);
    k_prescale16<<<pblk, 256, 0, stream>>>(x, dis, xd);
    k_fill4<<<e4blk, 256, 0, stream>>>(src, dst, cursor, csr_src);

    // layer 1: h2s = fp16(dis * (relu(gather(xd)@W1 + b1) + x))
    k_fused<1><<<fblk, 256, 0, stream>>>(row_start, csr_src, dis, xd, W1, b1, x, h2s);
    // layer 2: out = gather(h2s)@W2 + b2   (fp32 out)
    k_fused<0><<<fblk, 256, 0, stream>>>(row_start, csr_src, dis, h2s, W2, b2, nullptr, out);
}

// Round 11
// 196.008 us; speedup vs baseline: 15.2868x; 1.3925x over previous
//
#include <hip/hip_runtime.h>
#include <hip/hip_fp16.h>

#define N_NODES 50000
#define N_EDGES 800000
#define NF 128
#define N4 (N_NODES / 4)
#define SCAN_BLKS ((N4 + 255) / 256)   // 49
#define TILE 32                         // rows per fused block

typedef _Float16 half4v __attribute__((ext_vector_type(4)));
typedef _Float16 half8v __attribute__((ext_vector_type(8)));
typedef float    f32x4  __attribute__((ext_vector_type(4)));

// ---------------- CSR build ----------------

__global__ __launch_bounds__(256)
void k_count4(const int* __restrict__ dst, int* __restrict__ cnt) {
    int i = blockIdx.x * 256 + threadIdx.x;
    if (i < N_EDGES / 4) {
        int4 d = ((const int4*)dst)[i];
        atomicAdd(&cnt[d.x], 1);
        atomicAdd(&cnt[d.y], 1);
        atomicAdd(&cnt[d.z], 1);
        atomicAdd(&cnt[d.w], 1);
    }
}

__global__ __launch_bounds__(256)
void k_blksum(const int* __restrict__ cnt, int* __restrict__ blksum) {
    __shared__ int ls[256];
    const int t = threadIdx.x;
    int gi = blockIdx.x * 256 + t;           // int4 index
    int s = 0;
    if (gi < N4) {
        int4 c = ((const int4*)cnt)[gi];
        s = c.x + c.y + c.z + c.w;
    }
    ls[t] = s;
    __syncthreads();
    for (int off = 128; off > 0; off >>= 1) {
        if (t < off) ls[t] += ls[t + off];
        __syncthreads();
    }
    if (t == 0) blksum[blockIdx.x] = ls[0];
}

__global__ __launch_bounds__(64)
void k_scanblk(const int* __restrict__ blksum, int* __restrict__ blkoff) {
    __shared__ int ps[64];
    const int t = threadIdx.x;
    int v = (t < SCAN_BLKS) ? blksum[t] : 0;
    ps[t] = v;
    __syncthreads();
    const int my = v;
    for (int off = 1; off < 64; off <<= 1) {
        int u = (t >= off) ? ps[t - off] : 0;
        __syncthreads();
        ps[t] += u;
        __syncthreads();
    }
    if (t < SCAN_BLKS) blkoff[t] = ps[t] - my;
}

// phase C: exclusive scan + offset -> row_start & cursor (int4), dis folded in.
// cnt aliases cursor (each slot read before written by same thread).
__global__ __launch_bounds__(256)
void k_scan_c(const int* cnt, const int* __restrict__ blkoff,
              int* __restrict__ row_start, int* cursor, float* __restrict__ dis) {
    __shared__ int ps[256];
    const int t = threadIdx.x;
    const int b = blockIdx.x;
    const int gi = b * 256 + t;
    int4 c = make_int4(0, 0, 0, 0);
    if (gi < N4) c = ((const int4*)cnt)[gi];
    int s = c.x + c.y + c.z + c.w;
    ps[t] = s;
    __syncthreads();
    const int my = s;
    for (int off = 1; off < 256; off <<= 1) {
        int u = (t >= off) ? ps[t - off] : 0;
        __syncthreads();
        ps[t] += u;
        __syncthreads();
    }
    if (gi < N4) {
        int r0 = ps[t] - my + blkoff[b];
        int r1 = r0 + c.x, r2 = r1 + c.y, r3 = r2 + c.z;
        int4 r = make_int4(r0, r1, r2, r3);
        ((int4*)row_start)[gi] = r;
        ((int4*)cursor)[gi] = r;
        ((float4*)dis)[gi] = make_float4(
            rsqrtf((float)(1 + c.x)), rsqrtf((float)(1 + c.y)),
            rsqrtf((float)(1 + c.z)), rsqrtf((float)(1 + c.w)));
    }
    if (b == 0 && t == 0) row_start[N_NODES] = N_EDGES;
}

// xd16[n] = fp16(dis[n] * x[n])
__global__ __launch_bounds__(256)
void k_prescale16(const float* __restrict__ x, const float* __restrict__ dis,
                  __half* __restrict__ xd) {
    int i = blockIdx.x * 256 + threadIdx.x;
    if (i < N_NODES * (NF / 4)) {
        float d = dis[i >> 5];
        float4 v = ((const float4*)x)[i];
        union { __half2 h[2]; uint2 u; } pk;
        pk.h[0] = __floats2half2_rn(d * v.x, d * v.y);
        pk.h[1] = __floats2half2_rn(d * v.z, d * v.w);
        ((uint2*)xd)[i] = pk.u;
    }
}

__global__ __launch_bounds__(256)
void k_fill4(const int* __restrict__ src, const int* __restrict__ dst,
             int* __restrict__ cursor, int* __restrict__ csr_src) {
    int i = blockIdx.x * 256 + threadIdx.x;
    if (i < N_EDGES / 4) {
        int4 s = ((const int4*)src)[i];
        int4 d = ((const int4*)dst)[i];
        csr_src[atomicAdd(&cursor[d.x], 1)] = s.x;
        csr_src[atomicAdd(&cursor[d.y], 1)] = s.y;
        csr_src[atomicAdd(&cursor[d.z], 1)] = s.z;
        csr_src[atomicAdd(&cursor[d.w], 1)] = s.w;
    }
}

// W [128][128] f32 -> fp16 B-fragment layout Wf[ct][s][kb][col][e]
//   element (k = s*32+kb*8+e, n = ct*16+col). Handles W1 then W2.
__global__ __launch_bounds__(256)
void k_wcvt(const float* __restrict__ W1, const float* __restrict__ W2,
            _Float16* __restrict__ wf1, _Float16* __restrict__ wf2) {
    int i = blockIdx.x * 256 + threadIdx.x;   // 0..32767
    const float* W = (i < 16384) ? W1 : W2;
    _Float16* Wf = (i < 16384) ? wf1 : wf2;
    int j = i & 16383;
    int e = j & 7, col = (j >> 3) & 15, kb = (j >> 7) & 3, s = (j >> 9) & 3, ct = j >> 11;
    Wf[j] = (_Float16)W[(size_t)(s * 32 + kb * 8 + e) * NF + ct * 16 + col];
}

// ---------------- fused gather(fp16) + MFMA GEMM ----------------
// Gather: TILE=32 rows, 256 threads; wave owns 8 rows; 32-lane halves split
// each row's edge list, 8-deep unroll. Result written to LDS in A-fragment
// fp16 layout [s][kb][row][8] (264-halfword group stride, bank-friendly).
// GEMM: per wave 2 row-tiles x 2 col-tiles (cols 32w..32w+31), 4 k-steps of
// mfma_f32_16x16x32_f16 with B-frags from the pre-converted Wf (L1-hot).
// C/D: col=lane&15, row=(lane>>4)*4+reg.
// MODE 1: h2s16 = fp16( dis[row] * (relu(acc+b) + skip_f32) );  MODE 0: f32 out.

__device__ inline float4 ld16(const uint2* __restrict__ f2, size_t idx) {
    uint2 u = f2[idx];
    __half2 h0 = __builtin_bit_cast(__half2, u.x);
    __half2 h1 = __builtin_bit_cast(__half2, u.y);
    float2 a = __half22float2(h0);
    float2 b = __half22float2(h1);
    return make_float4(a.x, a.y, b.x, b.y);
}

#define ACC4(f) do { a.x += f.x; a.y += f.y; a.z += f.z; a.w += f.w; } while (0)

template <int MODE>
__global__ __launch_bounds__(256, 6)
void k_fused(const int* __restrict__ row_start, const int* __restrict__ csr_src,
             const float* __restrict__ dis, const __half* __restrict__ featd,
             const _Float16* __restrict__ Wf, const float* __restrict__ bias,
             const float* __restrict__ skip, void* __restrict__ C) {
    __shared__ _Float16 xs16[4 * 4 * 264];   // [s][kb] groups of 264, 8448 B
    const int t = threadIdx.x;
    const int row0 = blockIdx.x * TILE;
    const uint2* f2 = (const uint2*)featd;   // row stride = 32 uint2

    {   // ---- gather phase ----
        const int wave = t >> 6;          // 0..3
        const int lane = t & 63;
        const int half = lane >> 5;
        const int hl = lane & 31;
        for (int i = 0; i < 8; i++) {
            const int r = wave * 8 + i;
            const int n = row0 + r;
            float4 a = make_float4(0.f, 0.f, 0.f, 0.f);
            if (n < N_NODES) {
                const int st = row_start[n], en = row_start[n + 1];
                const int hh = (en - st + 1) >> 1;
                int j        = half ? st + hh : st;
                const int je = half ? en : st + hh;
                if (half == 0) a = ld16(f2, (size_t)n * 32 + hl);  // self loop
                for (; j + 7 < je; j += 8) {
                    int s0 = csr_src[j],     s1 = csr_src[j + 1];
                    int s2 = csr_src[j + 2], s3 = csr_src[j + 3];
                    int s4 = csr_src[j + 4], s5 = csr_src[j + 5];
                    int s6 = csr_src[j + 6], s7 = csr_src[j + 7];
                    float4 f0 = ld16(f2, (size_t)s0 * 32 + hl);
                    float4 f1 = ld16(f2, (size_t)s1 * 32 + hl);
                    float4 g2 = ld16(f2, (size_t)s2 * 32 + hl);
                    float4 f3 = ld16(f2, (size_t)s3 * 32 + hl);
                    float4 g4 = ld16(f2, (size_t)s4 * 32 + hl);
                    float4 f5 = ld16(f2, (size_t)s5 * 32 + hl);
                    float4 g6 = ld16(f2, (size_t)s6 * 32 + hl);
                    float4 f7 = ld16(f2, (size_t)s7 * 32 + hl);
                    ACC4(f0); ACC4(f1); ACC4(g2); ACC4(f3);
                    ACC4(g4); ACC4(f5); ACC4(g6); ACC4(f7);
                }
                for (; j + 3 < je; j += 4) {
                    int s0 = csr_src[j],     s1 = csr_src[j + 1];
                    int s2 = csr_src[j + 2], s3 = csr_src[j + 3];
                    float4 f0 = ld16(f2, (size_t)s0 * 32 + hl);
                    float4 f1 = ld16(f2, (size_t)s1 * 32 + hl);
                    float4 g2 = ld16(f2, (size_t)s2 * 32 + hl);
                    float4 f3 = ld16(f2, (size_t)s3 * 32 + hl);
                    ACC4(f0); ACC4(f1); ACC4(g2); ACC4(f3);
                }
                for (; j < je; ++j) {
                    float4 f = ld16(f2, (size_t)csr_src[j] * 32 + hl);
                    ACC4(f);
                }
            }
            a.x += __shfl_down(a.x, 32);
            a.y += __shfl_down(a.y, 32);
            a.z += __shfl_down(a.z, 32);
            a.w += __shfl_down(a.w, 32);
            if (half == 0) {
                const float dn = (n < N_NODES) ? dis[n] : 0.f;
                // A-fragment layout: f = hl*4 -> s=hl>>3, kb=(hl>>1)&3, e=(hl&1)*4
                const int s_ = hl >> 3, kb = (hl >> 1) & 3, e = (hl & 1) * 4;
                const int idx = (s_ * 4 + kb) * 264 + r * 8 + e;
                half4v h;
                h[0] = (_Float16)(a.x * dn); h[1] = (_Float16)(a.y * dn);
                h[2] = (_Float16)(a.z * dn); h[3] = (_Float16)(a.w * dn);
                *(half4v*)(xs16 + idx) = h;
            }
        }
    }
    __syncthreads();

    // ---- MFMA GEMM phase ----
    const int w = t >> 6;      // wave 0..3 -> cols 32w..32w+31
    const int l = t & 63;
    const int lc = l & 15;     // frag col / A row
    const int lk = l >> 4;     // k-block 0..3
    f32x4 acc[2][2];
#pragma unroll
    for (int rt = 0; rt < 2; rt++)
#pragma unroll
        for (int c = 0; c < 2; c++) acc[rt][c] = (f32x4)0.f;

#pragma unroll
    for (int s = 0; s < 4; s++) {
        half8v aF[2], bF[2];
#pragma unroll
        for (int rt = 0; rt < 2; rt++)
            aF[rt] = *(half8v*)(xs16 + (s * 4 + lk) * 264 + (rt * 16 + lc) * 8);
#pragma unroll
        for (int c = 0; c < 2; c++) {
            int ct = 2 * w + c;
            bF[c] = *(const half8v*)(Wf + (((ct * 4 + s) * 4 + lk) * 16 + lc) * 8);
        }
#pragma unroll
        for (int rt = 0; rt < 2; rt++)
#pragma unroll
            for (int c = 0; c < 2; c++)
                acc[rt][c] = __builtin_amdgcn_mfma_f32_16x16x32_f16(
                    aF[rt], bF[c], acc[rt][c], 0, 0, 0);
    }

    // ---- epilogue ----
#pragma unroll
    for (int c = 0; c < 2; c++) {
        const int col = w * 32 + c * 16 + lc;
        const float bcol = bias[col];
#pragma unroll
        for (int rt = 0; rt < 2; rt++) {
#pragma unroll
            for (int j = 0; j < 4; j++) {
                const int row = row0 + rt * 16 + lk * 4 + j;
                if (row < N_NODES) {
                    float v = acc[rt][c][j] + bcol;
                    if (MODE == 1) {
                        float dn = dis[row];
                        float sk = skip[(size_t)row * NF + col];
                        float o = dn * (fmaxf(v, 0.f) + sk);
                        ((__half*)C)[(size_t)row * NF + col] = __float2half(o);
                    } else {
                        ((float*)C)[(size_t)row * NF + col] = v;
                    }
                }
            }
        }
    }
}

// ---------------- launch ----------------

extern "C" void kernel_launch(void* const* d_in, const int* in_sizes, int n_in,
                              void* d_out, int out_size, void* d_ws, size_t ws_size,
                              hipStream_t stream) {
    const int*   ei = (const int*)d_in[0];
    const float* x  = (const float*)d_in[1];
    const float* W1 = (const float*)d_in[2];
    const float* b1 = (const float*)d_in[3];
    const float* W2 = (const float*)d_in[4];
    const float* b2 = (const float*)d_in[5];
    float* out = (float*)d_out;

    const int* src = ei;             // edge_index[0]
    const int* dst = ei + N_EDGES;   // edge_index[1]

    // workspace layout (within previously-validated ~29.4 MB footprint)
    char* w = (char*)d_ws;
    float*    dis       = (float*)(w);                   // [N]
    int*      row_start = (int*)  (w + 200192);          // [N+1]
    int*      cursor    = (int*)  (w + 400640);          // [N] (cnt aliases)
    int*      csr_src   = (int*)  (w + 600832);          // [E] 3.2 MB
    __half*   h2s       = (__half*)(w + 3801088);        // [N*128] fp16 12.8 MB
    _Float16* wf1       = (_Float16*)(w + 16601600);     // 32 KB
    _Float16* wf2       = (_Float16*)(w + 16634368);     // 32 KB
    int*      blk       = (int*)  (w + 29427712);        // [64+64]
    __half*   xd        = (__half*)out;                  // d_out as fp16 scratch
    int*      cnt       = cursor;

    const int e4blk = (N_EDGES / 4 + 255) / 256;
    const int pblk  = (N_NODES * (NF / 4) + 255) / 256;
    const int fblk  = (N_NODES + TILE - 1) / TILE;

    // CSR build + dis + prescale(fp16) + W conversion
    hipMemsetAsync(cnt, 0, N_NODES * sizeof(int), stream);
    k_count4<<<e4blk, 256, 0, stream>>>(dst, cnt);
    k_blksum<<<SCAN_BLKS, 256, 0, stream>>>(cnt, blk);
    k_scanblk<<<1, 64, 0, stream>>>(blk, blk + 64);
    k_scan_c<<<SCAN_BLKS, 256, 0, stream>>>(cnt, blk + 64, row_start, cursor, dis);
    k_prescale16<<<pblk, 256, 0, stream>>>(x, dis, xd);
    k_wcvt<<<128, 256, 0, stream>>>(W1, W2, wf1, wf2);
    k_fill4<<<e4blk, 256, 0, stream>>>(src, dst, cursor, csr_src);

    // layer 1: h2s = fp16(dis * (relu(gather(xd)@W1 + b1) + x))
    k_fused<1><<<fblk, 256, 0, stream>>>(row_start, csr_src, dis, xd, wf1, b1, x, h2s);
    // layer 2: out = gather(h2s)@W2 + b2   (fp32 out)
    k_fused<0><<<fblk, 256, 0, stream>>>(row_start, csr_src, dis, h2s, wf2, b2, nullptr, out);
}

// Round 12
// 142.098 us; speedup vs baseline: 21.0863x; 1.3794x over previous
//
#include <hip/hip_runtime.h>
#include <hip/hip_fp16.h>

#define N_NODES 50000
#define N_EDGES 800000
#define NF 128
#define TILE 32                         // rows per fused block
#define NB 98                           // ceil(50000/512) dst-buckets
#define BSHIFT 9                        // 512 nodes per bucket
#define BNODES 512
#define EPB 4096                        // edges per partition block
#define PBLKS ((N_EDGES + EPB - 1) / EPB)   // 196

typedef _Float16 half4v __attribute__((ext_vector_type(4)));
typedef _Float16 half8v __attribute__((ext_vector_type(8)));
typedef float    f32x4  __attribute__((ext_vector_type(4)));

// ---------------- bucketed CSR build (LDS atomics, line-friendly writes) ----

__global__ __launch_bounds__(256)
void k_bcount(const int* __restrict__ dst, int* __restrict__ bcnt) {
    __shared__ int h[NB];
    const int t = threadIdx.x;
    if (t < NB) h[t] = 0;
    __syncthreads();
    const int base4 = blockIdx.x * (EPB / 4);
#pragma unroll
    for (int k = 0; k < 4; k++) {
        int i4 = base4 + k * 256 + t;
        if (i4 < N_EDGES / 4) {
            int4 d = ((const int4*)dst)[i4];
            atomicAdd(&h[d.x >> BSHIFT], 1);
            atomicAdd(&h[d.y >> BSHIFT], 1);
            atomicAdd(&h[d.z >> BSHIFT], 1);
            atomicAdd(&h[d.w >> BSHIFT], 1);
        }
    }
    __syncthreads();
    if (t < NB && h[t]) atomicAdd(&bcnt[t], h[t]);
}

__global__ __launch_bounds__(128)
void k_bscan(const int* __restrict__ bcnt, int* __restrict__ boff,
             int* __restrict__ bcur) {
    __shared__ int ps[128];
    const int t = threadIdx.x;
    int v = (t < NB) ? bcnt[t] : 0;
    ps[t] = v;
    __syncthreads();
    const int my = v;
    for (int off = 1; off < 128; off <<= 1) {
        int u = (t >= off) ? ps[t - off] : 0;
        __syncthreads();
        ps[t] += u;
        __syncthreads();
    }
    if (t < NB) { int e = ps[t] - my; boff[t] = e; bcur[t] = e; }
    if (t == 0) boff[NB] = N_EDGES;
}

__global__ __launch_bounds__(256)
void k_bplace(const int* __restrict__ src, const int* __restrict__ dst,
              int* __restrict__ bcur, int2* __restrict__ ebuf) {
    __shared__ int h[NB];
    const int t = threadIdx.x;
    if (t < NB) h[t] = 0;
    __syncthreads();
    const int base4 = blockIdx.x * (EPB / 4);
#pragma unroll
    for (int k = 0; k < 4; k++) {
        int i4 = base4 + k * 256 + t;
        if (i4 < N_EDGES / 4) {
            int4 d = ((const int4*)dst)[i4];
            atomicAdd(&h[d.x >> BSHIFT], 1);
            atomicAdd(&h[d.y >> BSHIFT], 1);
            atomicAdd(&h[d.z >> BSHIFT], 1);
            atomicAdd(&h[d.w >> BSHIFT], 1);
        }
    }
    __syncthreads();
    if (t < NB && h[t]) h[t] = atomicAdd(&bcur[t], h[t]);   // count -> run base
    __syncthreads();
#pragma unroll
    for (int k = 0; k < 4; k++) {
        int i4 = base4 + k * 256 + t;
        if (i4 < N_EDGES / 4) {
            int4 d = ((const int4*)dst)[i4];
            int4 s = ((const int4*)src)[i4];
            int p;
            p = atomicAdd(&h[d.x >> BSHIFT], 1); ebuf[p] = make_int2(s.x, d.x);
            p = atomicAdd(&h[d.y >> BSHIFT], 1); ebuf[p] = make_int2(s.y, d.y);
            p = atomicAdd(&h[d.z >> BSHIFT], 1); ebuf[p] = make_int2(s.z, d.z);
            p = atomicAdd(&h[d.w >> BSHIFT], 1); ebuf[p] = make_int2(s.w, d.w);
        }
    }
}

// one block per bucket: per-dst count (LDS) -> scan -> row_start+dis+csr fill
__global__ __launch_bounds__(256)
void k_count_fill(const int* __restrict__ boff, const int2* __restrict__ ebuf,
                  int* __restrict__ row_start, int* __restrict__ csr_src,
                  float* __restrict__ dis) {
    __shared__ int cnt[BNODES];
    __shared__ int ps[256];
    const int t = threadIdx.x;
    const int b = blockIdx.x;
    const int nbase = b << BSHIFT;
    const int nn = min(BNODES, N_NODES - nbase);
    cnt[t] = 0; cnt[t + 256] = 0;
    __syncthreads();
    const int e0 = boff[b], e1 = boff[b + 1];
    for (int i = e0 + t; i < e1; i += 256)
        atomicAdd(&cnt[ebuf[i].y - nbase], 1);
    __syncthreads();
    const int i0 = 2 * t, i1 = 2 * t + 1;
    const int a0 = cnt[i0], a1 = cnt[i1];
    int s = a0 + a1;
    ps[t] = s;
    __syncthreads();
    const int my = s;
    for (int off = 1; off < 256; off <<= 1) {
        int u = (t >= off) ? ps[t - off] : 0;
        __syncthreads();
        ps[t] += u;
        __syncthreads();
    }
    const int ex = ps[t] - my;               // exclusive prefix over pairs
    if (i0 < nn) {
        row_start[nbase + i0] = e0 + ex;
        dis[nbase + i0] = rsqrtf((float)(1 + a0));
    }
    if (i1 < nn) {
        row_start[nbase + i1] = e0 + ex + a0;
        dis[nbase + i1] = rsqrtf((float)(1 + a1));
    }
    __syncthreads();
    cnt[i0] = ex; cnt[i1] = ex + a0;         // cursors (own slots only)
    __syncthreads();
    for (int i = e0 + t; i < e1; i += 256) {
        int2 sd = ebuf[i];
        int p = atomicAdd(&cnt[sd.y - nbase], 1);
        csr_src[e0 + p] = sd.x;
    }
    if (b == 0 && t == 0) row_start[N_NODES] = N_EDGES;
}

// xd16[n] = fp16(dis[n] * x[n])
__global__ __launch_bounds__(256)
void k_prescale16(const float* __restrict__ x, const float* __restrict__ dis,
                  __half* __restrict__ xd) {
    int i = blockIdx.x * 256 + threadIdx.x;
    if (i < N_NODES * (NF / 4)) {
        float d = dis[i >> 5];
        float4 v = ((const float4*)x)[i];
        union { __half2 h[2]; uint2 u; } pk;
        pk.h[0] = __floats2half2_rn(d * v.x, d * v.y);
        pk.h[1] = __floats2half2_rn(d * v.z, d * v.w);
        ((uint2*)xd)[i] = pk.u;
    }
}

// W [128][128] f32 -> fp16 B-fragment layout Wf[ct][s][kb][col][e]
__global__ __launch_bounds__(256)
void k_wcvt(const float* __restrict__ W1, const float* __restrict__ W2,
            _Float16* __restrict__ wf1, _Float16* __restrict__ wf2) {
    int i = blockIdx.x * 256 + threadIdx.x;   // 0..32767
    const float* W = (i < 16384) ? W1 : W2;
    _Float16* Wf = (i < 16384) ? wf1 : wf2;
    int j = i & 16383;
    int e = j & 7, col = (j >> 3) & 15, kb = (j >> 7) & 3, s = (j >> 9) & 3, ct = j >> 11;
    Wf[j] = (_Float16)W[(size_t)(s * 32 + kb * 8 + e) * NF + ct * 16 + col];
}

// ---------------- fused gather(fp16) + MFMA GEMM ----------------

__device__ inline float4 ld16(const uint2* __restrict__ f2, size_t idx) {
    uint2 u = f2[idx];
    __half2 h0 = __builtin_bit_cast(__half2, u.x);
    __half2 h1 = __builtin_bit_cast(__half2, u.y);
    float2 a = __half22float2(h0);
    float2 b = __half22float2(h1);
    return make_float4(a.x, a.y, b.x, b.y);
}

#define ACC4(f) do { a.x += f.x; a.y += f.y; a.z += f.z; a.w += f.w; } while (0)

template <int MODE>
__global__ __launch_bounds__(256, 8)
void k_fused(const int* __restrict__ row_start, const int* __restrict__ csr_src,
             const float* __restrict__ dis, const __half* __restrict__ featd,
             const _Float16* __restrict__ Wf, const float* __restrict__ bias,
             const float* __restrict__ skip, void* __restrict__ C) {
    __shared__ _Float16 xs16[4 * 4 * 264];   // A-frag groups, 8448 B
    const int t = threadIdx.x;
    const int row0 = blockIdx.x * TILE;
    const uint2* f2 = (const uint2*)featd;   // row stride = 32 uint2

    {   // ---- gather phase ----
        const int wave = t >> 6;          // 0..3
        const int lane = t & 63;
        const int half = lane >> 5;
        const int hl = lane & 31;
        for (int i = 0; i < 8; i++) {
            const int r = wave * 8 + i;
            const int n = row0 + r;
            float4 a = make_float4(0.f, 0.f, 0.f, 0.f);
            if (n < N_NODES) {
                const int st = row_start[n], en = row_start[n + 1];
                const int hh = (en - st + 1) >> 1;
                int j        = half ? st + hh : st;
                const int je = half ? en : st + hh;
                if (half == 0) a = ld16(f2, (size_t)n * 32 + hl);  // self loop
                for (; j + 7 < je; j += 8) {
                    int s0 = csr_src[j],     s1 = csr_src[j + 1];
                    int s2 = csr_src[j + 2], s3 = csr_src[j + 3];
                    int s4 = csr_src[j + 4], s5 = csr_src[j + 5];
                    int s6 = csr_src[j + 6], s7 = csr_src[j + 7];
                    float4 f0 = ld16(f2, (size_t)s0 * 32 + hl);
                    float4 f1 = ld16(f2, (size_t)s1 * 32 + hl);
                    float4 g2 = ld16(f2, (size_t)s2 * 32 + hl);
                    float4 f3 = ld16(f2, (size_t)s3 * 32 + hl);
                    float4 g4 = ld16(f2, (size_t)s4 * 32 + hl);
                    float4 f5 = ld16(f2, (size_t)s5 * 32 + hl);
                    float4 g6 = ld16(f2, (size_t)s6 * 32 + hl);
                    float4 f7 = ld16(f2, (size_t)s7 * 32 + hl);
                    ACC4(f0); ACC4(f1); ACC4(g2); ACC4(f3);
                    ACC4(g4); ACC4(f5); ACC4(g6); ACC4(f7);
                }
                for (; j + 3 < je; j += 4) {
                    int s0 = csr_src[j],     s1 = csr_src[j + 1];
                    int s2 = csr_src[j + 2], s3 = csr_src[j + 3];
                    float4 f0 = ld16(f2, (size_t)s0 * 32 + hl);
                    float4 f1 = ld16(f2, (size_t)s1 * 32 + hl);
                    float4 g2 = ld16(f2, (size_t)s2 * 32 + hl);
                    float4 f3 = ld16(f2, (size_t)s3 * 32 + hl);
                    ACC4(f0); ACC4(f1); ACC4(g2); ACC4(f3);
                }
                for (; j < je; ++j) {
                    float4 f = ld16(f2, (size_t)csr_src[j] * 32 + hl);
                    ACC4(f);
                }
            }
            a.x += __shfl_down(a.x, 32);
            a.y += __shfl_down(a.y, 32);
            a.z += __shfl_down(a.z, 32);
            a.w += __shfl_down(a.w, 32);
            if (half == 0) {
                const float dn = (n < N_NODES) ? dis[n] : 0.f;
                const int s_ = hl >> 3, kb = (hl >> 1) & 3, e = (hl & 1) * 4;
                const int idx = (s_ * 4 + kb) * 264 + r * 8 + e;
                half4v h;
                h[0] = (_Float16)(a.x * dn); h[1] = (_Float16)(a.y * dn);
                h[2] = (_Float16)(a.z * dn); h[3] = (_Float16)(a.w * dn);
                *(half4v*)(xs16 + idx) = h;
            }
        }
    }
    __syncthreads();

    // ---- MFMA GEMM phase ----
    const int w = t >> 6;      // wave 0..3 -> cols 32w..32w+31
    const int l = t & 63;
    const int lc = l & 15;     // frag col / A row
    const int lk = l >> 4;     // k-block 0..3
    f32x4 acc[2][2];
#pragma unroll
    for (int rt = 0; rt < 2; rt++)
#pragma unroll
        for (int c = 0; c < 2; c++) acc[rt][c] = (f32x4)0.f;

#pragma unroll
    for (int s = 0; s < 4; s++) {
        half8v aF[2], bF[2];
#pragma unroll
        for (int rt = 0; rt < 2; rt++)
            aF[rt] = *(half8v*)(xs16 + (s * 4 + lk) * 264 + (rt * 16 + lc) * 8);
#pragma unroll
        for (int c = 0; c < 2; c++) {
            int ct = 2 * w + c;
            bF[c] = *(const half8v*)(Wf + (((ct * 4 + s) * 4 + lk) * 16 + lc) * 8);
        }
#pragma unroll
        for (int rt = 0; rt < 2; rt++)
#pragma unroll
            for (int c = 0; c < 2; c++)
                acc[rt][c] = __builtin_amdgcn_mfma_f32_16x16x32_f16(
                    aF[rt], bF[c], acc[rt][c], 0, 0, 0);
    }

    // ---- epilogue ----
#pragma unroll
    for (int c = 0; c < 2; c++) {
        const int col = w * 32 + c * 16 + lc;
        const float bcol = bias[col];
#pragma unroll
        for (int rt = 0; rt < 2; rt++) {
#pragma unroll
            for (int j = 0; j < 4; j++) {
                const int row = row0 + rt * 16 + lk * 4 + j;
                if (row < N_NODES) {
                    float v = acc[rt][c][j] + bcol;
                    if (MODE == 1) {
                        float dn = dis[row];
                        float sk = skip[(size_t)row * NF + col];
                        float o = dn * (fmaxf(v, 0.f) + sk);
                        ((__half*)C)[(size_t)row * NF + col] = __float2half(o);
                    } else {
                        ((float*)C)[(size_t)row * NF + col] = v;
                    }
                }
            }
        }
    }
}

// ---------------- launch ----------------

extern "C" void kernel_launch(void* const* d_in, const int* in_sizes, int n_in,
                              void* d_out, int out_size, void* d_ws, size_t ws_size,
                              hipStream_t stream) {
    const int*   ei = (const int*)d_in[0];
    const float* x  = (const float*)d_in[1];
    const float* W1 = (const float*)d_in[2];
    const float* b1 = (const float*)d_in[3];
    const float* W2 = (const float*)d_in[4];
    const float* b2 = (const float*)d_in[5];
    float* out = (float*)d_out;

    const int* src = ei;             // edge_index[0]
    const int* dst = ei + N_EDGES;   // edge_index[1]

    // workspace layout (~23.3 MB, within previously-validated footprint)
    char* w = (char*)d_ws;
    float*    dis       = (float*)(w);                   // [N]
    int*      row_start = (int*)  (w + 200192);          // [N+1]
    int*      csr_src   = (int*)  (w + 600832);          // [E] 3.2 MB
    __half*   h2s       = (__half*)(w + 3801088);        // [N*128] fp16 12.8 MB
    _Float16* wf1       = (_Float16*)(w + 16601600);     // 32 KB
    _Float16* wf2       = (_Float16*)(w + 16634368);     // 32 KB
    int2*     ebuf      = (int2*)  (w + 16777216);       // [E] 6.4 MB
    int*      bcnt      = (int*)   (w + 23200000);       // [NB]
    int*      boff      = (int*)   (w + 23200512);       // [NB+1]
    int*      bcur      = (int*)   (w + 23201024);       // [NB]
    __half*   xd        = (__half*)out;                  // d_out as fp16 scratch

    const int pblk = (N_NODES * (NF / 4) + 255) / 256;
    const int fblk = (N_NODES + TILE - 1) / TILE;

    // bucketed CSR build + dis + prescale(fp16) + W conversion
    hipMemsetAsync(bcnt, 0, NB * sizeof(int), stream);
    k_bcount<<<PBLKS, 256, 0, stream>>>(dst, bcnt);
    k_bscan<<<1, 128, 0, stream>>>(bcnt, boff, bcur);
    k_bplace<<<PBLKS, 256, 0, stream>>>(src, dst, bcur, ebuf);
    k_count_fill<<<NB, 256, 0, stream>>>(boff, ebuf, row_start, csr_src, dis);
    k_prescale16<<<pblk, 256, 0, stream>>>(x, dis, xd);
    k_wcvt<<<128, 256, 0, stream>>>(W1, W2, wf1, wf2);

    // layer 1: h2s = fp16(dis * (relu(gather(xd)@W1 + b1) + x))
    k_fused<1><<<fblk, 256, 0, stream>>>(row_start, csr_src, dis, xd, wf1, b1, x, h2s);
    // layer 2: out = gather(h2s)@W2 + b2   (fp32 out)
    k_fused<0><<<fblk, 256, 0, stream>>>(row_start, csr_src, dis, h2s, wf2, b2, nullptr, out);
}

// Round 13
// 135.605 us; speedup vs baseline: 22.0960x; 1.0479x over previous
//
#include <hip/hip_runtime.h>
#include <hip/hip_fp16.h>

#define N_NODES 50000
#define N_EDGES 800000
#define NF 128
#define TILE 16                          // rows per fused block
#define NB 98                            // ceil(50000/512) dst-buckets
#define BSHIFT 9
#define BNODES 512
#define ECAP 10240                       // bucket capacity (mean 8163, 6sig~540)
#define EPB 4096                         // edges per partition block
#define PBLKS ((N_EDGES + EPB - 1) / EPB)   // 196
#define PRE_BLKS (N_NODES * (NF / 4) / 256) // 6250
#define WCVT_BLKS 128

typedef _Float16 half4v __attribute__((ext_vector_type(4)));
typedef _Float16 half8v __attribute__((ext_vector_type(8)));
typedef float    f32x4  __attribute__((ext_vector_type(4)));

// ---------------- bucketed CSR build (fixed-capacity buckets) ----------------

__global__ __launch_bounds__(256)
void k_bplace(const int* __restrict__ src, const int* __restrict__ dst,
              int* __restrict__ bcur, int2* __restrict__ ebuf) {
    __shared__ int h[NB];
    const int t = threadIdx.x;
    if (t < NB) h[t] = 0;
    __syncthreads();
    const int base4 = blockIdx.x * (EPB / 4);
#pragma unroll
    for (int k = 0; k < 4; k++) {
        int i4 = base4 + k * 256 + t;
        if (i4 < N_EDGES / 4) {
            int4 d = ((const int4*)dst)[i4];
            atomicAdd(&h[d.x >> BSHIFT], 1);
            atomicAdd(&h[d.y >> BSHIFT], 1);
            atomicAdd(&h[d.z >> BSHIFT], 1);
            atomicAdd(&h[d.w >> BSHIFT], 1);
        }
    }
    __syncthreads();
    if (t < NB && h[t]) h[t] = atomicAdd(&bcur[t], h[t]);   // count -> run base
    __syncthreads();
#pragma unroll
    for (int k = 0; k < 4; k++) {
        int i4 = base4 + k * 256 + t;
        if (i4 < N_EDGES / 4) {
            int4 d = ((const int4*)dst)[i4];
            int4 s = ((const int4*)src)[i4];
            int b_, p;
            b_ = d.x >> BSHIFT; p = min(atomicAdd(&h[b_], 1), ECAP - 1);
            ebuf[(size_t)b_ * ECAP + p] = make_int2(s.x, d.x);
            b_ = d.y >> BSHIFT; p = min(atomicAdd(&h[b_], 1), ECAP - 1);
            ebuf[(size_t)b_ * ECAP + p] = make_int2(s.y, d.y);
            b_ = d.z >> BSHIFT; p = min(atomicAdd(&h[b_], 1), ECAP - 1);
            ebuf[(size_t)b_ * ECAP + p] = make_int2(s.z, d.z);
            b_ = d.w >> BSHIFT; p = min(atomicAdd(&h[b_], 1), ECAP - 1);
            ebuf[(size_t)b_ * ECAP + p] = make_int2(s.w, d.w);
        }
    }
}

// one block per bucket: per-dst count (LDS) -> scan -> rs2 + dis + csr fill
__global__ __launch_bounds__(256)
void k_count_fill(const int* __restrict__ bcur, const int2* __restrict__ ebuf,
                  int2* __restrict__ rs2, int* __restrict__ csr_src,
                  float* __restrict__ dis) {
    __shared__ int cnt[BNODES];
    __shared__ int ps[256];
    const int t = threadIdx.x;
    const int b = blockIdx.x;
    const int nbase = b << BSHIFT;
    const int nn = min(BNODES, N_NODES - nbase);
    cnt[t] = 0; cnt[t + 256] = 0;
    __syncthreads();
    const int e0 = b * ECAP;
    const int e1 = e0 + min(bcur[b], ECAP);
    for (int i = e0 + t; i < e1; i += 256)
        atomicAdd(&cnt[ebuf[i].y - nbase], 1);
    __syncthreads();
    const int i0 = 2 * t, i1 = 2 * t + 1;
    const int a0 = cnt[i0], a1 = cnt[i1];
    int s = a0 + a1;
    ps[t] = s;
    __syncthreads();
    const int my = s;
    for (int off = 1; off < 256; off <<= 1) {
        int u = (t >= off) ? ps[t - off] : 0;
        __syncthreads();
        ps[t] += u;
        __syncthreads();
    }
    const int ex = ps[t] - my;               // exclusive prefix over pairs
    if (i0 < nn) {
        rs2[nbase + i0] = make_int2(e0 + ex, e0 + ex + a0);
        dis[nbase + i0] = rsqrtf((float)(1 + a0));
    }
    if (i1 < nn) {
        rs2[nbase + i1] = make_int2(e0 + ex + a0, e0 + ex + a0 + a1);
        dis[nbase + i1] = rsqrtf((float)(1 + a1));
    }
    __syncthreads();
    cnt[i0] = ex; cnt[i1] = ex + a0;         // bucket-local cursors
    __syncthreads();
    for (int i = e0 + t; i < e1; i += 256) {
        int2 sd = ebuf[i];
        int p = atomicAdd(&cnt[sd.y - nbase], 1);
        csr_src[e0 + p] = sd.x;
    }
}

// merged: xd16 = fp16(dis*x)  (blocks 0..PRE_BLKS-1)  |  W->fp16 B-frag (rest)
__global__ __launch_bounds__(256)
void k_prep(const float* __restrict__ x, const float* __restrict__ dis,
            __half* __restrict__ xd,
            const float* __restrict__ W1, const float* __restrict__ W2,
            _Float16* __restrict__ wf1, _Float16* __restrict__ wf2) {
    const int t = threadIdx.x;
    if (blockIdx.x < PRE_BLKS) {
        int i = blockIdx.x * 256 + t;
        float d = dis[i >> 5];
        float4 v = ((const float4*)x)[i];
        union { __half2 h[2]; uint2 u; } pk;
        pk.h[0] = __floats2half2_rn(d * v.x, d * v.y);
        pk.h[1] = __floats2half2_rn(d * v.z, d * v.w);
        ((uint2*)xd)[i] = pk.u;
    } else {
        int i = (blockIdx.x - PRE_BLKS) * 256 + t;   // 0..32767
        const float* W = (i < 16384) ? W1 : W2;
        _Float16* Wf = (i < 16384) ? wf1 : wf2;
        int j = i & 16383;
        int e = j & 7, col = (j >> 3) & 15, kb = (j >> 7) & 3,
            s = (j >> 9) & 3, ct = j >> 11;
        Wf[j] = (_Float16)W[(size_t)(s * 32 + kb * 8 + e) * NF + ct * 16 + col];
    }
}

// ---------------- fused gather(fp16) + MFMA GEMM, TILE=16 ----------------
// Gather: 256 threads = 4 waves; wave owns 4 rows; 32-lane halves split each
// row's edge list, 8-deep unroll. A-frag LDS [s][kb] groups of 136 halves.
// GEMM: wave w -> cols 32w..32w+31, 1 row-tile, 4 k-steps mfma_16x16x32_f16.
// MODE 1: h2s16 = fp16( dis[row] * (relu(acc+b) + skip_f32) );  MODE 0: f32.

__device__ inline float4 ld16(const uint2* __restrict__ f2, size_t idx) {
    uint2 u = f2[idx];
    __half2 h0 = __builtin_bit_cast(__half2, u.x);
    __half2 h1 = __builtin_bit_cast(__half2, u.y);
    float2 a = __half22float2(h0);
    float2 b = __half22float2(h1);
    return make_float4(a.x, a.y, b.x, b.y);
}

#define ACC4(f) do { a.x += f.x; a.y += f.y; a.z += f.z; a.w += f.w; } while (0)

template <int MODE>
__global__ __launch_bounds__(256, 8)
void k_fused(const int2* __restrict__ rs2, const int* __restrict__ csr_src,
             const float* __restrict__ dis, const __half* __restrict__ featd,
             const _Float16* __restrict__ Wf, const float* __restrict__ bias,
             const float* __restrict__ skip, void* __restrict__ C) {
    __shared__ _Float16 xs16[4 * 4 * 136];   // A-frag groups, 4352 B
    const int t = threadIdx.x;
    const int row0 = blockIdx.x * TILE;
    const uint2* f2 = (const uint2*)featd;   // row stride = 32 uint2

    {   // ---- gather phase ----
        const int wave = t >> 6;          // 0..3
        const int lane = t & 63;
        const int half = lane >> 5;
        const int hl = lane & 31;
        for (int i = 0; i < 4; i++) {
            const int r = wave * 4 + i;
            const int n = row0 + r;
            float4 a = make_float4(0.f, 0.f, 0.f, 0.f);
            if (n < N_NODES) {
                const int2 se = rs2[n];
                const int st = se.x, en = se.y;
                const int hh = (en - st + 1) >> 1;
                int j        = half ? st + hh : st;
                const int je = half ? en : st + hh;
                if (half == 0) a = ld16(f2, (size_t)n * 32 + hl);  // self loop
                for (; j + 7 < je; j += 8) {
                    int s0 = csr_src[j],     s1 = csr_src[j + 1];
                    int s2 = csr_src[j + 2], s3 = csr_src[j + 3];
                    int s4 = csr_src[j + 4], s5 = csr_src[j + 5];
                    int s6 = csr_src[j + 6], s7 = csr_src[j + 7];
                    float4 f0 = ld16(f2, (size_t)s0 * 32 + hl);
                    float4 f1 = ld16(f2, (size_t)s1 * 32 + hl);
                    float4 g2 = ld16(f2, (size_t)s2 * 32 + hl);
                    float4 f3 = ld16(f2, (size_t)s3 * 32 + hl);
                    float4 g4 = ld16(f2, (size_t)s4 * 32 + hl);
                    float4 f5 = ld16(f2, (size_t)s5 * 32 + hl);
                    float4 g6 = ld16(f2, (size_t)s6 * 32 + hl);
                    float4 f7 = ld16(f2, (size_t)s7 * 32 + hl);
                    ACC4(f0); ACC4(f1); ACC4(g2); ACC4(f3);
                    ACC4(g4); ACC4(f5); ACC4(g6); ACC4(f7);
                }
                for (; j + 3 < je; j += 4) {
                    int s0 = csr_src[j],     s1 = csr_src[j + 1];
                    int s2 = csr_src[j + 2], s3 = csr_src[j + 3];
                    float4 f0 = ld16(f2, (size_t)s0 * 32 + hl);
                    float4 f1 = ld16(f2, (size_t)s1 * 32 + hl);
                    float4 g2 = ld16(f2, (size_t)s2 * 32 + hl);
                    float4 f3 = ld16(f2, (size_t)s3 * 32 + hl);
                    ACC4(f0); ACC4(f1); ACC4(g2); ACC4(f3);
                }
                for (; j < je; ++j) {
                    float4 f = ld16(f2, (size_t)csr_src[j] * 32 + hl);
                    ACC4(f);
                }
            }
            a.x += __shfl_down(a.x, 32);
            a.y += __shfl_down(a.y, 32);
            a.z += __shfl_down(a.z, 32);
            a.w += __shfl_down(a.w, 32);
            if (half == 0) {
                const float dn = (n < N_NODES) ? dis[n] : 0.f;
                const int s_ = hl >> 3, kb = (hl >> 1) & 3, e = (hl & 1) * 4;
                const int idx = (s_ * 4 + kb) * 136 + r * 8 + e;
                half4v h;
                h[0] = (_Float16)(a.x * dn); h[1] = (_Float16)(a.y * dn);
                h[2] = (_Float16)(a.z * dn); h[3] = (_Float16)(a.w * dn);
                *(half4v*)(xs16 + idx) = h;
            }
        }
    }
    __syncthreads();

    // ---- MFMA GEMM phase ----
    const int w = t >> 6;      // wave 0..3 -> cols 32w..32w+31
    const int l = t & 63;
    const int lc = l & 15;     // frag col / A row
    const int lk = l >> 4;     // k-block 0..3
    f32x4 acc[2];
    acc[0] = (f32x4)0.f; acc[1] = (f32x4)0.f;

#pragma unroll
    for (int s = 0; s < 4; s++) {
        half8v aF = *(half8v*)(xs16 + (s * 4 + lk) * 136 + lc * 8);
#pragma unroll
        for (int c = 0; c < 2; c++) {
            int ct = 2 * w + c;
            half8v bF = *(const half8v*)(Wf + (((ct * 4 + s) * 4 + lk) * 16 + lc) * 8);
            acc[c] = __builtin_amdgcn_mfma_f32_16x16x32_f16(aF, bF, acc[c], 0, 0, 0);
        }
    }

    // ---- epilogue ----
#pragma unroll
    for (int c = 0; c < 2; c++) {
        const int col = w * 32 + c * 16 + lc;
        const float bcol = bias[col];
#pragma unroll
        for (int j = 0; j < 4; j++) {
            const int row = row0 + lk * 4 + j;
            if (row < N_NODES) {
                float v = acc[c][j] + bcol;
                if (MODE == 1) {
                    float dn = dis[row];
                    float sk = skip[(size_t)row * NF + col];
                    float o = dn * (fmaxf(v, 0.f) + sk);
                    ((__half*)C)[(size_t)row * NF + col] = __float2half(o);
                } else {
                    ((float*)C)[(size_t)row * NF + col] = v;
                }
            }
        }
    }
}

// ---------------- launch ----------------

extern "C" void kernel_launch(void* const* d_in, const int* in_sizes, int n_in,
                              void* d_out, int out_size, void* d_ws, size_t ws_size,
                              hipStream_t stream) {
    const int*   ei = (const int*)d_in[0];
    const float* x  = (const float*)d_in[1];
    const float* W1 = (const float*)d_in[2];
    const float* b1 = (const float*)d_in[3];
    const float* W2 = (const float*)d_in[4];
    const float* b2 = (const float*)d_in[5];
    float* out = (float*)d_out;

    const int* src = ei;             // edge_index[0]
    const int* dst = ei + N_EDGES;   // edge_index[1]

    // workspace layout (~25.6 MB)
    char* w = (char*)d_ws;
    float*    dis     = (float*)(w);                    // [N]          200000
    int2*     rs2     = (int2*)  (w + 200704);          // [N] int2     400000
    int*      csr_src = (int*)   (w + 600832);          // [NB*ECAP]    4.01 MB
    int2*     ebuf    = (int2*)  (w + 4615168);         // [NB*ECAP]    8.03 MB
    __half*   h2s     = (__half*)(w + 12643328);        // [N*128] fp16 12.8 MB
    _Float16* wf1     = (_Float16*)(w + 25443584);      // 32 KB
    _Float16* wf2     = (_Float16*)(w + 25476352);      // 32 KB
    int*      bcur    = (int*)   (w + 25509120);        // [NB]
    __half*   xd      = (__half*)out;                   // d_out as fp16 scratch

    const int fblk = (N_NODES + TILE - 1) / TILE;       // 3125

    // CSR build + dis + prescale/wcvt
    hipMemsetAsync(bcur, 0, NB * sizeof(int), stream);
    k_bplace<<<PBLKS, 256, 0, stream>>>(src, dst, bcur, ebuf);
    k_count_fill<<<NB, 256, 0, stream>>>(bcur, ebuf, rs2, csr_src, dis);
    k_prep<<<PRE_BLKS + WCVT_BLKS, 256, 0, stream>>>(x, dis, xd, W1, W2, wf1, wf2);

    // layer 1: h2s = fp16(dis * (relu(gather(xd)@W1 + b1) + x))
    k_fused<1><<<fblk, 256, 0, stream>>>(rs2, csr_src, dis, xd, wf1, b1, x, h2s);
    // layer 2: out = gather(h2s)@W2 + b2   (fp32 out)
    k_fused<0><<<fblk, 256, 0, stream>>>(rs2, csr_src, dis, h2s, wf2, b2, nullptr, out);
}

// Round 16
// 135.225 us; speedup vs baseline: 22.1580x; 1.0028x over previous
//
#include <hip/hip_runtime.h>
#include <hip/hip_fp16.h>

#define N_NODES 50000
#define N_EDGES 800000
#define NF 128
#define TILE 16                          // rows per fused block
#define NB 98                            // ceil(50000/512) dst-buckets
#define BSHIFT 9
#define BNODES 512
#define ECAP 10240                       // bucket capacity (mean 8163, 23 sigma)
#define EPB 4096                         // edges per partition block
#define PBLKS ((N_EDGES + EPB - 1) / EPB)   // 196
#define PRE_BLKS (N_NODES * (NF / 4) / 256) // 6250
#define WCVT_BLKS 128

typedef _Float16 half4v __attribute__((ext_vector_type(4)));
typedef _Float16 half8v __attribute__((ext_vector_type(8)));
typedef float    f32x4  __attribute__((ext_vector_type(4)));

// ---------------- bucketed CSR build (fixed-capacity buckets) ----------------

__global__ __launch_bounds__(256)
void k_bplace(const int* __restrict__ src, const int* __restrict__ dst,
              int* __restrict__ bcur, int2* __restrict__ ebuf) {
    __shared__ int h[NB];
    const int t = threadIdx.x;
    if (t < NB) h[t] = 0;
    __syncthreads();
    const int base4 = blockIdx.x * (EPB / 4);
#pragma unroll
    for (int k = 0; k < 4; k++) {
        int i4 = base4 + k * 256 + t;
        if (i4 < N_EDGES / 4) {
            int4 d = ((const int4*)dst)[i4];
            atomicAdd(&h[d.x >> BSHIFT], 1);
            atomicAdd(&h[d.y >> BSHIFT], 1);
            atomicAdd(&h[d.z >> BSHIFT], 1);
            atomicAdd(&h[d.w >> BSHIFT], 1);
        }
    }
    __syncthreads();
    if (t < NB && h[t]) h[t] = atomicAdd(&bcur[t], h[t]);   // count -> run base
    __syncthreads();
#pragma unroll
    for (int k = 0; k < 4; k++) {
        int i4 = base4 + k * 256 + t;
        if (i4 < N_EDGES / 4) {
            int4 d = ((const int4*)dst)[i4];
            int4 s = ((const int4*)src)[i4];
            int b_, p;
            b_ = d.x >> BSHIFT; p = min(atomicAdd(&h[b_], 1), ECAP - 1);
            ebuf[(size_t)b_ * ECAP + p] = make_int2(s.x, d.x);
            b_ = d.y >> BSHIFT; p = min(atomicAdd(&h[b_], 1), ECAP - 1);
            ebuf[(size_t)b_ * ECAP + p] = make_int2(s.y, d.y);
            b_ = d.z >> BSHIFT; p = min(atomicAdd(&h[b_], 1), ECAP - 1);
            ebuf[(size_t)b_ * ECAP + p] = make_int2(s.z, d.z);
            b_ = d.w >> BSHIFT; p = min(atomicAdd(&h[b_], 1), ECAP - 1);
            ebuf[(size_t)b_ * ECAP + p] = make_int2(s.w, d.w);
        }
    }
}

// one block per bucket: per-dst count (LDS) -> scan -> rs2 + dis + disi + fill
__global__ __launch_bounds__(256)
void k_count_fill(const int* __restrict__ bcur, const int2* __restrict__ ebuf,
                  int2* __restrict__ rs2, int* __restrict__ csr_src,
                  float* __restrict__ dis, float* __restrict__ disi) {
    __shared__ int cnt[BNODES];
    __shared__ int ps[256];
    const int t = threadIdx.x;
    const int b = blockIdx.x;
    const int nbase = b << BSHIFT;
    const int nn = min(BNODES, N_NODES - nbase);
    cnt[t] = 0; cnt[t + 256] = 0;
    __syncthreads();
    const int e0 = b * ECAP;
    const int e1 = e0 + min(bcur[b], ECAP);
    for (int i = e0 + t; i < e1; i += 256)
        atomicAdd(&cnt[ebuf[i].y - nbase], 1);
    __syncthreads();
    const int i0 = 2 * t, i1 = 2 * t + 1;
    const int a0 = cnt[i0], a1 = cnt[i1];
    int s = a0 + a1;
    ps[t] = s;
    __syncthreads();
    const int my = s;
    for (int off = 1; off < 256; off <<= 1) {
        int u = (t >= off) ? ps[t - off] : 0;
        __syncthreads();
        ps[t] += u;
        __syncthreads();
    }
    const int ex = ps[t] - my;               // exclusive prefix over pairs
    if (i0 < nn) {
        rs2[nbase + i0] = make_int2(e0 + ex, e0 + ex + a0);
        float f = (float)(1 + a0);
        dis[nbase + i0] = rsqrtf(f);
        disi[nbase + i0] = sqrtf(f);
    }
    if (i1 < nn) {
        rs2[nbase + i1] = make_int2(e0 + ex + a0, e0 + ex + a0 + a1);
        float f = (float)(1 + a1);
        dis[nbase + i1] = rsqrtf(f);
        disi[nbase + i1] = sqrtf(f);
    }
    __syncthreads();
    cnt[i0] = ex; cnt[i1] = ex + a0;         // bucket-local cursors
    __syncthreads();
    for (int i = e0 + t; i < e1; i += 256) {
        int2 sd = ebuf[i];
        int p = atomicAdd(&cnt[sd.y - nbase], 1);
        csr_src[e0 + p] = sd.x;
    }
}

// merged: xd16 = fp16(dis*x)  (blocks 0..PRE_BLKS-1)  |  W->fp16 B-frag (rest)
__global__ __launch_bounds__(256)
void k_prep(const float* __restrict__ x, const float* __restrict__ dis,
            __half* __restrict__ xd,
            const float* __restrict__ W1, const float* __restrict__ W2,
            _Float16* __restrict__ wf1, _Float16* __restrict__ wf2) {
    const int t = threadIdx.x;
    if (blockIdx.x < PRE_BLKS) {
        int i = blockIdx.x * 256 + t;
        float d = dis[i >> 5];
        float4 v = ((const float4*)x)[i];
        union { __half2 h[2]; uint2 u; } pk;
        pk.h[0] = __floats2half2_rn(d * v.x, d * v.y);
        pk.h[1] = __floats2half2_rn(d * v.z, d * v.w);
        ((uint2*)xd)[i] = pk.u;
    } else {
        int i = (blockIdx.x - PRE_BLKS) * 256 + t;   // 0..32767
        const float* W = (i < 16384) ? W1 : W2;
        _Float16* Wf = (i < 16384) ? wf1 : wf2;
        int j = i & 16383;
        int e = j & 7, col = (j >> 3) & 15, kb = (j >> 7) & 3,
            s = (j >> 9) & 3, ct = j >> 11;
        Wf[j] = (_Float16)W[(size_t)(s * 32 + kb * 8 + e) * NF + ct * 16 + col];
    }
}

// ---------------- fused gather(fp16) + MFMA GEMM, TILE=16 ----------------
// Gather (round-13 verified form): 4 waves; wave owns 4 rows; 32-lane halves
// split each row's edge list, 8-deep unroll, shfl_down combine, half0 stores
// A-frag LDS [s][kb] groups of 136 halves.
// GEMM: wave w -> cols 32w..32w+31, 4 k-steps mfma_f32_16x16x32_f16.
// MODE 1: h2s16 = fp16( dis[row] * (relu(acc+b) + xd16[row]*disi[row]) )
// MODE 0: C_f32 = acc + b

__device__ inline float4 ld16(const uint2* __restrict__ f2, size_t idx) {
    uint2 u = f2[idx];
    __half2 h0 = __builtin_bit_cast(__half2, u.x);
    __half2 h1 = __builtin_bit_cast(__half2, u.y);
    float2 a = __half22float2(h0);
    float2 b = __half22float2(h1);
    return make_float4(a.x, a.y, b.x, b.y);
}

#define ACC4(f) do { a.x += f.x; a.y += f.y; a.z += f.z; a.w += f.w; } while (0)

template <int MODE>
__global__ __launch_bounds__(256, 8)
void k_fused(const int2* __restrict__ rs2, const int* __restrict__ csr_src,
             const float* __restrict__ dis, const float* __restrict__ disi,
             const __half* __restrict__ featd, const _Float16* __restrict__ Wf,
             const float* __restrict__ bias, void* __restrict__ C) {
    __shared__ _Float16 xs16[4 * 4 * 136];   // A-frag groups, 4352 B
    const int t = threadIdx.x;
    const int row0 = blockIdx.x * TILE;
    const uint2* f2 = (const uint2*)featd;   // row stride = 32 uint2

    {   // ---- gather phase (round-13 verified) ----
        const int wave = t >> 6;          // 0..3
        const int lane = t & 63;
        const int half = lane >> 5;
        const int hl = lane & 31;
        for (int i = 0; i < 4; i++) {
            const int r = wave * 4 + i;
            const int n = row0 + r;
            float4 a = make_float4(0.f, 0.f, 0.f, 0.f);
            if (n < N_NODES) {
                const int2 se = rs2[n];
                const int st = se.x, en = se.y;
                const int hh = (en - st + 1) >> 1;
                int j        = half ? st + hh : st;
                const int je = half ? en : st + hh;
                if (half == 0) a = ld16(f2, (size_t)n * 32 + hl);  // self loop
                for (; j + 7 < je; j += 8) {
                    int s0 = csr_src[j],     s1 = csr_src[j + 1];
                    int s2 = csr_src[j + 2], s3 = csr_src[j + 3];
                    int s4 = csr_src[j + 4], s5 = csr_src[j + 5];
                    int s6 = csr_src[j + 6], s7 = csr_src[j + 7];
                    float4 f0 = ld16(f2, (size_t)s0 * 32 + hl);
                    float4 f1 = ld16(f2, (size_t)s1 * 32 + hl);
                    float4 g2 = ld16(f2, (size_t)s2 * 32 + hl);
                    float4 f3 = ld16(f2, (size_t)s3 * 32 + hl);
                    float4 g4 = ld16(f2, (size_t)s4 * 32 + hl);
                    float4 f5 = ld16(f2, (size_t)s5 * 32 + hl);
                    float4 g6 = ld16(f2, (size_t)s6 * 32 + hl);
                    float4 f7 = ld16(f2, (size_t)s7 * 32 + hl);
                    ACC4(f0); ACC4(f1); ACC4(g2); ACC4(f3);
                    ACC4(g4); ACC4(f5); ACC4(g6); ACC4(f7);
                }
                for (; j + 3 < je; j += 4) {
                    int s0 = csr_src[j],     s1 = csr_src[j + 1];
                    int s2 = csr_src[j + 2], s3 = csr_src[j + 3];
                    float4 f0 = ld16(f2, (size_t)s0 * 32 + hl);
                    float4 f1 = ld16(f2, (size_t)s1 * 32 + hl);
                    float4 g2 = ld16(f2, (size_t)s2 * 32 + hl);
                    float4 f3 = ld16(f2, (size_t)s3 * 32 + hl);
                    ACC4(f0); ACC4(f1); ACC4(g2); ACC4(f3);
                }
                for (; j < je; ++j) {
                    float4 f = ld16(f2, (size_t)csr_src[j] * 32 + hl);
                    ACC4(f);
                }
            }
            a.x += __shfl_down(a.x, 32);
            a.y += __shfl_down(a.y, 32);
            a.z += __shfl_down(a.z, 32);
            a.w += __shfl_down(a.w, 32);
            if (half == 0) {
                const float dn = (n < N_NODES) ? dis[n] : 0.f;
                const int s_ = hl >> 3, kb = (hl >> 1) & 3, e = (hl & 1) * 4;
                const int idx = (s_ * 4 + kb) * 136 + r * 8 + e;
                half4v h;
                h[0] = (_Float16)(a.x * dn); h[1] = (_Float16)(a.y * dn);
                h[2] = (_Float16)(a.z * dn); h[3] = (_Float16)(a.w * dn);
                *(half4v*)(xs16 + idx) = h;
            }
        }
    }
    __syncthreads();

    // ---- MFMA GEMM phase ----
    const int w = t >> 6;      // wave 0..3 -> cols 32w..32w+31
    const int l = t & 63;
    const int lc = l & 15;     // frag col / A row
    const int lk = l >> 4;     // k-block 0..3
    f32x4 acc[2];
    acc[0] = (f32x4)0.f; acc[1] = (f32x4)0.f;

#pragma unroll
    for (int s = 0; s < 4; s++) {
        half8v aF = *(half8v*)(xs16 + (s * 4 + lk) * 136 + lc * 8);
#pragma unroll
        for (int c = 0; c < 2; c++) {
            int ct = 2 * w + c;
            half8v bF = *(const half8v*)(Wf + (((ct * 4 + s) * 4 + lk) * 16 + lc) * 8);
            acc[c] = __builtin_amdgcn_mfma_f32_16x16x32_f16(aF, bF, acc[c], 0, 0, 0);
        }
    }

    // ---- epilogue ----
#pragma unroll
    for (int c = 0; c < 2; c++) {
        const int col = w * 32 + c * 16 + lc;
        const float bcol = bias[col];
#pragma unroll
        for (int j = 0; j < 4; j++) {
            const int row = row0 + lk * 4 + j;
            if (row < N_NODES) {
                float v = acc[c][j] + bcol;
                if (MODE == 1) {
                    float dn = dis[row];
                    // skip = x = xd16 * sqrt(1+deg)  (exact rescale of fp16 xd)
                    float sk = __half2float(featd[(size_t)row * NF + col]) * disi[row];
                    float o = dn * (fmaxf(v, 0.f) + sk);
                    ((__half*)C)[(size_t)row * NF + col] = __float2half(o);
                } else {
                    ((float*)C)[(size_t)row * NF + col] = v;
                }
            }
        }
    }
}

// ---------------- launch ----------------

extern "C" void kernel_launch(void* const* d_in, const int* in_sizes, int n_in,
                              void* d_out, int out_size, void* d_ws, size_t ws_size,
                              hipStream_t stream) {
    const int*   ei = (const int*)d_in[0];
    const float* x  = (const float*)d_in[1];
    const float* W1 = (const float*)d_in[2];
    const float* b1 = (const float*)d_in[3];
    const float* W2 = (const float*)d_in[4];
    const float* b2 = (const float*)d_in[5];
    float* out = (float*)d_out;

    const int* src = ei;             // edge_index[0]
    const int* dst = ei + N_EDGES;   // edge_index[1]

    // workspace layout (~25.7 MB)
    char* w = (char*)d_ws;
    float*    dis     = (float*)(w);                    // [N]          200000
    int2*     rs2     = (int2*)  (w + 200704);          // [N] int2     400000
    int*      csr_src = (int*)   (w + 600832);          // [NB*ECAP]    4.01 MB
    int2*     ebuf    = (int2*)  (w + 4615168);         // [NB*ECAP]    8.03 MB
    __half*   h2s     = (__half*)(w + 12643328);        // [N*128] fp16 12.8 MB
    _Float16* wf1     = (_Float16*)(w + 25443584);      // 32 KB
    _Float16* wf2     = (_Float16*)(w + 25476352);      // 32 KB
    int*      bcur    = (int*)   (w + 25509120);        // [NB]
    float*    disi    = (float*)(w + 25510144);         // [N]          200000
    __half*   xd      = (__half*)out;                   // d_out as fp16 scratch

    const int fblk = N_NODES / TILE;                    // 3125 exact

    // CSR build + dis/disi + prescale/wcvt
    hipMemsetAsync(bcur, 0, NB * sizeof(int), stream);
    k_bplace<<<PBLKS, 256, 0, stream>>>(src, dst, bcur, ebuf);
    k_count_fill<<<NB, 256, 0, stream>>>(bcur, ebuf, rs2, csr_src, dis, disi);
    k_prep<<<PRE_BLKS + WCVT_BLKS, 256, 0, stream>>>(x, dis, xd, W1, W2, wf1, wf2);

    // layer 1: h2s = fp16(dis * (relu(gather(xd)@W1 + b1) + x))
    k_fused<1><<<fblk, 256, 0, stream>>>(rs2, csr_src, dis, disi, xd, wf1, b1, h2s);
    // layer 2: out = gather(h2s)@W2 + b2   (fp32 out)
    k_fused<0><<<fblk, 256, 0, stream>>>(rs2, csr_src, dis, disi, h2s, wf2, b2, out);
}

// Round 17
// 126.335 us; speedup vs baseline: 23.7172x; 1.0704x over previous
//
#include <hip/hip_runtime.h>
#include <hip/hip_fp16.h>

#define N_NODES 50000
#define N_EDGES 800000
#define NF 128
#define TILE 16                          // rows per fused block
#define NB 98                            // ceil(50000/512) dst-buckets
#define BSHIFT 9
#define BNODES 512
#define ECAP 10240                       // bucket capacity (mean 8163, 23 sigma)
#define EPB 4096                         // edges per partition block
#define PBLKS ((N_EDGES + EPB - 1) / EPB)   // 196
#define WCVT_BLKS 128

typedef _Float16 half8v __attribute__((ext_vector_type(8)));
typedef float    f32x4  __attribute__((ext_vector_type(4)));

// ---------------- bucketed CSR build + W conversion ----------------
// blocks [0, PBLKS): partition edges into fixed-capacity dst-buckets
// blocks [PBLKS, PBLKS+WCVT_BLKS): W1/W2 -> fp16 B-fragment layout

__global__ __launch_bounds__(256)
void k_bplace(const int* __restrict__ src, const int* __restrict__ dst,
              int* __restrict__ bcur, int2* __restrict__ ebuf,
              const float* __restrict__ W1, const float* __restrict__ W2,
              _Float16* __restrict__ wf1, _Float16* __restrict__ wf2) {
    __shared__ int h[NB];
    const int t = threadIdx.x;
    if (blockIdx.x >= PBLKS) {       // ---- wcvt path ----
        int i = (blockIdx.x - PBLKS) * 256 + t;   // 0..32767
        const float* W = (i < 16384) ? W1 : W2;
        _Float16* Wf = (i < 16384) ? wf1 : wf2;
        int j = i & 16383;
        int e = j & 7, col = (j >> 3) & 15, kb = (j >> 7) & 3,
            s = (j >> 9) & 3, ct = j >> 11;
        Wf[j] = (_Float16)W[(size_t)(s * 32 + kb * 8 + e) * NF + ct * 16 + col];
        return;
    }
    if (t < NB) h[t] = 0;
    __syncthreads();
    const int base4 = blockIdx.x * (EPB / 4);
#pragma unroll
    for (int k = 0; k < 4; k++) {
        int i4 = base4 + k * 256 + t;
        if (i4 < N_EDGES / 4) {
            int4 d = ((const int4*)dst)[i4];
            atomicAdd(&h[d.x >> BSHIFT], 1);
            atomicAdd(&h[d.y >> BSHIFT], 1);
            atomicAdd(&h[d.z >> BSHIFT], 1);
            atomicAdd(&h[d.w >> BSHIFT], 1);
        }
    }
    __syncthreads();
    if (t < NB && h[t]) h[t] = atomicAdd(&bcur[t], h[t]);   // count -> run base
    __syncthreads();
#pragma unroll
    for (int k = 0; k < 4; k++) {
        int i4 = base4 + k * 256 + t;
        if (i4 < N_EDGES / 4) {
            int4 d = ((const int4*)dst)[i4];
            int4 s = ((const int4*)src)[i4];
            int b_, p;
            b_ = d.x >> BSHIFT; p = min(atomicAdd(&h[b_], 1), ECAP - 1);
            ebuf[(size_t)b_ * ECAP + p] = make_int2(s.x, d.x);
            b_ = d.y >> BSHIFT; p = min(atomicAdd(&h[b_], 1), ECAP - 1);
            ebuf[(size_t)b_ * ECAP + p] = make_int2(s.y, d.y);
            b_ = d.z >> BSHIFT; p = min(atomicAdd(&h[b_], 1), ECAP - 1);
            ebuf[(size_t)b_ * ECAP + p] = make_int2(s.z, d.z);
            b_ = d.w >> BSHIFT; p = min(atomicAdd(&h[b_], 1), ECAP - 1);
            ebuf[(size_t)b_ * ECAP + p] = make_int2(s.w, d.w);
        }
    }
}

// one block per bucket: per-dst count (LDS) -> scan -> rs2/dis/disi + csr fill
// + fused prescale of this bucket's feature rows: xd16 = fp16(dis * x)

__global__ __launch_bounds__(256)
void k_count_fill(const int* __restrict__ bcur, const int2* __restrict__ ebuf,
                  int2* __restrict__ rs2, int* __restrict__ csr_src,
                  float* __restrict__ dis, float* __restrict__ disi,
                  const float* __restrict__ x, __half* __restrict__ xd) {
    __shared__ int cnt[BNODES];
    __shared__ int ps[256];
    __shared__ float sdis[BNODES];
    const int t = threadIdx.x;
    const int b = blockIdx.x;
    const int nbase = b << BSHIFT;
    const int nn = min(BNODES, N_NODES - nbase);
    cnt[t] = 0; cnt[t + 256] = 0;
    __syncthreads();
    const int e0 = b * ECAP;
    const int e1 = e0 + min(bcur[b], ECAP);
    for (int i = e0 + t; i < e1; i += 256)
        atomicAdd(&cnt[ebuf[i].y - nbase], 1);
    __syncthreads();
    const int i0 = 2 * t, i1 = 2 * t + 1;
    const int a0 = cnt[i0], a1 = cnt[i1];
    int s = a0 + a1;
    ps[t] = s;
    __syncthreads();
    const int my = s;
    for (int off = 1; off < 256; off <<= 1) {
        int u = (t >= off) ? ps[t - off] : 0;
        __syncthreads();
        ps[t] += u;
        __syncthreads();
    }
    const int ex = ps[t] - my;               // exclusive prefix over pairs
    {
        float f0 = (float)(1 + a0), f1 = (float)(1 + a1);
        float d0 = rsqrtf(f0), d1 = rsqrtf(f1);
        sdis[i0] = d0; sdis[i1] = d1;
        if (i0 < nn) {
            rs2[nbase + i0] = make_int2(e0 + ex, e0 + ex + a0);
            dis[nbase + i0] = d0;
            disi[nbase + i0] = sqrtf(f0);
        }
        if (i1 < nn) {
            rs2[nbase + i1] = make_int2(e0 + ex + a0, e0 + ex + a0 + a1);
            dis[nbase + i1] = d1;
            disi[nbase + i1] = sqrtf(f1);
        }
    }
    __syncthreads();
    cnt[i0] = ex; cnt[i1] = ex + a0;         // bucket-local cursors
    __syncthreads();
    for (int i = e0 + t; i < e1; i += 256) {
        int2 sd = ebuf[i];
        int p = atomicAdd(&cnt[sd.y - nbase], 1);
        csr_src[e0 + p] = sd.x;
    }
    // ---- fused prescale for this bucket's rows ----
    const int total = nn * 32;               // 32 float4 per row
    for (int idx = t; idx < total; idx += 256) {
        int r = idx >> 5, c = idx & 31;
        float d = sdis[r];
        float4 v = ((const float4*)x)[(size_t)(nbase + r) * 32 + c];
        union { __half2 h[2]; uint2 u; } pk;
        pk.h[0] = __floats2half2_rn(d * v.x, d * v.y);
        pk.h[1] = __floats2half2_rn(d * v.z, d * v.w);
        ((uint2*)xd)[(size_t)(nbase + r) * 32 + c] = pk.u;
    }
}

// ---------------- fused gather(fp16) + MFMA GEMM, TILE=16 ----------------
// Gather: 4 waves x 4 groups of 16 lanes; each GROUP owns one full row
// (4 rows per wave CONCURRENT, not serial). Lane gl owns 8 feats (uint4,
// 16B). 8-deep unroll. No shuffle. A-frag store: k = gl*8+e exactly.
// GEMM: wave w -> cols 32w..32w+31, 4 k-steps mfma_f32_16x16x32_f16.
// MODE 1: h2s16 = fp16( dis[row] * (relu(acc+b) + xd16[row]*disi[row]) )
// MODE 0: C_f32 = acc + b

__device__ inline void ld32(const uint4* __restrict__ p, size_t idx,
                            float4& lo, float4& hi) {
    uint4 u = p[idx];
    float2 a = __half22float2(__builtin_bit_cast(__half2, u.x));
    float2 b = __half22float2(__builtin_bit_cast(__half2, u.y));
    float2 c = __half22float2(__builtin_bit_cast(__half2, u.z));
    float2 d = __half22float2(__builtin_bit_cast(__half2, u.w));
    lo = make_float4(a.x, a.y, b.x, b.y);
    hi = make_float4(c.x, c.y, d.x, d.y);
}

#define ACC8(l, h) do { \
    a0.x += l.x; a0.y += l.y; a0.z += l.z; a0.w += l.w; \
    a1.x += h.x; a1.y += h.y; a1.z += h.z; a1.w += h.w; } while (0)

template <int MODE>
__global__ __launch_bounds__(256, 7)
void k_fused(const int2* __restrict__ rs2, const int* __restrict__ csr_src,
             const float* __restrict__ dis, const float* __restrict__ disi,
             const __half* __restrict__ featd, const _Float16* __restrict__ Wf,
             const float* __restrict__ bias, void* __restrict__ C) {
    __shared__ __align__(16) _Float16 xs16[4 * 4 * 136];   // A-frag groups
    const int t = threadIdx.x;
    const int row0 = blockIdx.x * TILE;
    const uint4* f4p = (const uint4*)featd;  // row stride = 16 uint4

    {   // ---- gather phase: one full row per 16-lane group ----
        const int wave = t >> 6;          // 0..3
        const int g = (t >> 4) & 3;       // group in wave
        const int gl = t & 15;            // lane in group (owns 8 feats)
        const int r = wave * 4 + g;
        const int n = row0 + r;           // always < N_NODES (3125*16 exact)
        const int2 se = rs2[n];
        int j = se.x;
        const int je = se.y;
        float4 a0, a1;
        ld32(f4p, (size_t)n * 16 + gl, a0, a1);   // self loop
        for (; j + 7 < je; j += 8) {
            int s0 = csr_src[j],     s1 = csr_src[j + 1];
            int s2 = csr_src[j + 2], s3 = csr_src[j + 3];
            int s4 = csr_src[j + 4], s5 = csr_src[j + 5];
            int s6 = csr_src[j + 6], s7 = csr_src[j + 7];
            float4 l0, h0, l1, h1, l2, h2, l3, h3;
            float4 l4, h4, l5, h5, l6, h6, l7, h7;
            ld32(f4p, (size_t)s0 * 16 + gl, l0, h0);
            ld32(f4p, (size_t)s1 * 16 + gl, l1, h1);
            ld32(f4p, (size_t)s2 * 16 + gl, l2, h2);
            ld32(f4p, (size_t)s3 * 16 + gl, l3, h3);
            ld32(f4p, (size_t)s4 * 16 + gl, l4, h4);
            ld32(f4p, (size_t)s5 * 16 + gl, l5, h5);
            ld32(f4p, (size_t)s6 * 16 + gl, l6, h6);
            ld32(f4p, (size_t)s7 * 16 + gl, l7, h7);
            ACC8(l0, h0); ACC8(l1, h1); ACC8(l2, h2); ACC8(l3, h3);
            ACC8(l4, h4); ACC8(l5, h5); ACC8(l6, h6); ACC8(l7, h7);
        }
        for (; j + 3 < je; j += 4) {
            int s0 = csr_src[j],     s1 = csr_src[j + 1];
            int s2 = csr_src[j + 2], s3 = csr_src[j + 3];
            float4 l0, h0, l1, h1, l2, h2, l3, h3;
            ld32(f4p, (size_t)s0 * 16 + gl, l0, h0);
            ld32(f4p, (size_t)s1 * 16 + gl, l1, h1);
            ld32(f4p, (size_t)s2 * 16 + gl, l2, h2);
            ld32(f4p, (size_t)s3 * 16 + gl, l3, h3);
            ACC8(l0, h0); ACC8(l1, h1); ACC8(l2, h2); ACC8(l3, h3);
        }
        for (; j < je; ++j) {
            float4 l0, h0;
            ld32(f4p, (size_t)csr_src[j] * 16 + gl, l0, h0);
            ACC8(l0, h0);
        }
        const float dn = dis[n];
        // A-frag: feats gl*8+e -> k = (gl>>2)*32 + (gl&3)*8 + e = gl*8+e
        const int s_ = gl >> 2, kb = gl & 3;
        half8v h;
        h[0] = (_Float16)(a0.x * dn); h[1] = (_Float16)(a0.y * dn);
        h[2] = (_Float16)(a0.z * dn); h[3] = (_Float16)(a0.w * dn);
        h[4] = (_Float16)(a1.x * dn); h[5] = (_Float16)(a1.y * dn);
        h[6] = (_Float16)(a1.z * dn); h[7] = (_Float16)(a1.w * dn);
        *(half8v*)(xs16 + (s_ * 4 + kb) * 136 + r * 8) = h;
    }
    __syncthreads();

    // ---- MFMA GEMM phase ----
    const int w = t >> 6;      // wave 0..3 -> cols 32w..32w+31
    const int l = t & 63;
    const int lc = l & 15;     // frag col / A row
    const int lk = l >> 4;     // k-block 0..3
    f32x4 acc[2];
    acc[0] = (f32x4)0.f; acc[1] = (f32x4)0.f;

#pragma unroll
    for (int s = 0; s < 4; s++) {
        half8v aF = *(half8v*)(xs16 + (s * 4 + lk) * 136 + lc * 8);
#pragma unroll
        for (int c = 0; c < 2; c++) {
            int ct = 2 * w + c;
            half8v bF = *(const half8v*)(Wf + (((ct * 4 + s) * 4 + lk) * 16 + lc) * 8);
            acc[c] = __builtin_amdgcn_mfma_f32_16x16x32_f16(aF, bF, acc[c], 0, 0, 0);
        }
    }

    // ---- epilogue ----
#pragma unroll
    for (int c = 0; c < 2; c++) {
        const int col = w * 32 + c * 16 + lc;
        const float bcol = bias[col];
#pragma unroll
        for (int j = 0; j < 4; j++) {
            const int row = row0 + lk * 4 + j;
            float v = acc[c][j] + bcol;
            if (MODE == 1) {
                float dn = dis[row];
                // skip = x = xd16 * sqrt(1+deg)  (validated round 16)
                float sk = __half2float(featd[(size_t)row * NF + col]) * disi[row];
                float o = dn * (fmaxf(v, 0.f) + sk);
                ((__half*)C)[(size_t)row * NF + col] = __float2half(o);
            } else {
                ((float*)C)[(size_t)row * NF + col] = v;
            }
        }
    }
}

// ---------------- launch ----------------

extern "C" void kernel_launch(void* const* d_in, const int* in_sizes, int n_in,
                              void* d_out, int out_size, void* d_ws, size_t ws_size,
                              hipStream_t stream) {
    const int*   ei = (const int*)d_in[0];
    const float* x  = (const float*)d_in[1];
    const float* W1 = (const float*)d_in[2];
    const float* b1 = (const float*)d_in[3];
    const float* W2 = (const float*)d_in[4];
    const float* b2 = (const float*)d_in[5];
    float* out = (float*)d_out;

    const int* src = ei;             // edge_index[0]
    const int* dst = ei + N_EDGES;   // edge_index[1]

    // workspace layout (~25.7 MB)
    char* w = (char*)d_ws;
    float*    dis     = (float*)(w);                    // [N]          200000
    int2*     rs2     = (int2*)  (w + 200704);          // [N] int2     400000
    int*      csr_src = (int*)   (w + 600832);          // [NB*ECAP]    4.01 MB
    int2*     ebuf    = (int2*)  (w + 4615168);         // [NB*ECAP]    8.03 MB
    __half*   h2s     = (__half*)(w + 12643328);        // [N*128] fp16 12.8 MB
    _Float16* wf1     = (_Float16*)(w + 25443584);      // 32 KB
    _Float16* wf2     = (_Float16*)(w + 25476352);      // 32 KB
    int*      bcur    = (int*)   (w + 25509120);        // [NB]
    float*    disi    = (float*)(w + 25510144);         // [N]          200000
    __half*   xd      = (__half*)out;                   // d_out as fp16 scratch

    const int fblk = N_NODES / TILE;                    // 3125 exact

    // CSR build (+wcvt riding) -> count/fill (+prescale riding)
    hipMemsetAsync(bcur, 0, NB * sizeof(int), stream);
    k_bplace<<<PBLKS + WCVT_BLKS, 256, 0, stream>>>(src, dst, bcur, ebuf,
                                                    W1, W2, wf1, wf2);
    k_count_fill<<<NB, 256, 0, stream>>>(bcur, ebuf, rs2, csr_src, dis, disi,
                                         x, xd);

    // layer 1: h2s = fp16(dis * (relu(gather(xd)@W1 + b1) + x))
    k_fused<1><<<fblk, 256, 0, stream>>>(rs2, csr_src, dis, disi, xd, wf1, b1, h2s);
    // layer 2: out = gather(h2s)@W2 + b2   (fp32 out)
    k_fused<0><<<fblk, 256, 0, stream>>>(rs2, csr_src, dis, disi, h2s, wf2, b2, out);
}

// Round 18
// 104.443 us; speedup vs baseline: 28.6885x; 1.2096x over previous
//
#include <hip/hip_runtime.h>
#include <hip/hip_fp16.h>

#define N_NODES 50000
#define N_EDGES 800000
#define NF 128
#define TILE 16                          // rows per fused block
#define NB 391                           // ceil(50000/128) dst-buckets
#define BSHIFT 7                         // 128 nodes per bucket
#define BNODES 128
#define ECAP 2560                        // bucket capacity (mean 2048, 11 sigma)
#define EPB 4096                         // edges per partition block
#define PBLKS ((N_EDGES + EPB - 1) / EPB)   // 196
#define WCVT_BLKS 128

typedef _Float16 half8v __attribute__((ext_vector_type(8)));
typedef float    f32x4  __attribute__((ext_vector_type(4)));

// ---------------- bucketed CSR build + W conversion ----------------
// blocks [0, PBLKS): partition edges into fixed-capacity dst-buckets
// blocks [PBLKS, PBLKS+WCVT_BLKS): W1/W2 -> fp16 B-fragment layout

__global__ __launch_bounds__(256)
void k_bplace(const int* __restrict__ src, const int* __restrict__ dst,
              int* __restrict__ bcur, int2* __restrict__ ebuf,
              const float* __restrict__ W1, const float* __restrict__ W2,
              _Float16* __restrict__ wf1, _Float16* __restrict__ wf2) {
    __shared__ int h[NB];
    const int t = threadIdx.x;
    if (blockIdx.x >= PBLKS) {       // ---- wcvt path (uniform per block) ----
        int i = (blockIdx.x - PBLKS) * 256 + t;   // 0..32767
        const float* W = (i < 16384) ? W1 : W2;
        _Float16* Wf = (i < 16384) ? wf1 : wf2;
        int j = i & 16383;
        int e = j & 7, col = (j >> 3) & 15, kb = (j >> 7) & 3,
            s = (j >> 9) & 3, ct = j >> 11;
        Wf[j] = (_Float16)W[(size_t)(s * 32 + kb * 8 + e) * NF + ct * 16 + col];
        return;
    }
    for (int i = t; i < NB; i += 256) h[i] = 0;
    __syncthreads();
    const int base4 = blockIdx.x * (EPB / 4);
#pragma unroll
    for (int k = 0; k < 4; k++) {
        int i4 = base4 + k * 256 + t;
        if (i4 < N_EDGES / 4) {
            int4 d = ((const int4*)dst)[i4];
            atomicAdd(&h[d.x >> BSHIFT], 1);
            atomicAdd(&h[d.y >> BSHIFT], 1);
            atomicAdd(&h[d.z >> BSHIFT], 1);
            atomicAdd(&h[d.w >> BSHIFT], 1);
        }
    }
    __syncthreads();
    for (int i = t; i < NB; i += 256)
        if (h[i]) h[i] = atomicAdd(&bcur[i], h[i]);   // count -> run base
    __syncthreads();
#pragma unroll
    for (int k = 0; k < 4; k++) {
        int i4 = base4 + k * 256 + t;
        if (i4 < N_EDGES / 4) {
            int4 d = ((const int4*)dst)[i4];
            int4 s = ((const int4*)src)[i4];
            int b_, p;
            b_ = d.x >> BSHIFT; p = min(atomicAdd(&h[b_], 1), ECAP - 1);
            ebuf[(size_t)b_ * ECAP + p] = make_int2(s.x, d.x);
            b_ = d.y >> BSHIFT; p = min(atomicAdd(&h[b_], 1), ECAP - 1);
            ebuf[(size_t)b_ * ECAP + p] = make_int2(s.y, d.y);
            b_ = d.z >> BSHIFT; p = min(atomicAdd(&h[b_], 1), ECAP - 1);
            ebuf[(size_t)b_ * ECAP + p] = make_int2(s.z, d.z);
            b_ = d.w >> BSHIFT; p = min(atomicAdd(&h[b_], 1), ECAP - 1);
            ebuf[(size_t)b_ * ECAP + p] = make_int2(s.w, d.w);
        }
    }
}

// one block per bucket (128 nodes, ~2048 edges): LDS count -> scan ->
// rs2/dis/disi + csr fill + fused prescale xd16 = fp16(dis * x)

__global__ __launch_bounds__(256)
void k_count_fill(const int* __restrict__ bcur, const int2* __restrict__ ebuf,
                  int2* __restrict__ rs2, int* __restrict__ csr_src,
                  float* __restrict__ dis, float* __restrict__ disi,
                  const float* __restrict__ x, __half* __restrict__ xd) {
    __shared__ int cnt[BNODES];
    __shared__ int ps[256];
    __shared__ float sdis[BNODES];
    const int t = threadIdx.x;
    const int b = blockIdx.x;
    const int nbase = b << BSHIFT;
    const int nn = min(BNODES, N_NODES - nbase);
    if (t < BNODES) cnt[t] = 0;
    __syncthreads();
    const int e0 = b * ECAP;
    const int e1 = e0 + min(bcur[b], ECAP);
    for (int i = e0 + t; i < e1; i += 256)
        atomicAdd(&cnt[ebuf[i].y - nbase], 1);
    __syncthreads();
    const int a0 = (t < BNODES) ? cnt[t] : 0;
    ps[t] = a0;
    __syncthreads();
    for (int off = 1; off < BNODES; off <<= 1) {   // 7 steps cover t<128
        int u = (t >= off) ? ps[t - off] : 0;
        __syncthreads();
        ps[t] += u;
        __syncthreads();
    }
    const int ex = ps[t] - a0;               // exclusive prefix (t < BNODES)
    if (t < nn) {
        float f = (float)(1 + a0);
        float d = rsqrtf(f);
        rs2[nbase + t] = make_int2(e0 + ex, e0 + ex + a0);
        dis[nbase + t] = d;
        disi[nbase + t] = sqrtf(f);
        sdis[t] = d;
    } else if (t < BNODES) {
        sdis[t] = 0.f;
    }
    __syncthreads();
    if (t < BNODES) cnt[t] = ex;             // bucket-local cursors
    __syncthreads();
    for (int i = e0 + t; i < e1; i += 256) {
        int2 sd = ebuf[i];
        int p = atomicAdd(&cnt[sd.y - nbase], 1);
        csr_src[e0 + p] = sd.x;
    }
    // ---- fused prescale for this bucket's rows ----
    const int total = nn * 32;               // 32 float4 per row
    for (int idx = t; idx < total; idx += 256) {
        int r = idx >> 5, c = idx & 31;
        float d = sdis[r];
        float4 v = ((const float4*)x)[(size_t)(nbase + r) * 32 + c];
        union { __half2 h[2]; uint2 u; } pk;
        pk.h[0] = __floats2half2_rn(d * v.x, d * v.y);
        pk.h[1] = __floats2half2_rn(d * v.z, d * v.w);
        ((uint2*)xd)[(size_t)(nbase + r) * 32 + c] = pk.u;
    }
}

// ---------------- fused gather(fp16) + MFMA GEMM, TILE=16 ----------------
// (validated round 17)  Gather: 4 waves x 4 groups of 16 lanes; each group
// owns one full row concurrently; lane gl owns 8 feats (uint4). 8-deep
// unroll, no shuffle. A-frag store k = gl*8+e.
// GEMM: wave w -> cols 32w..32w+31, 4 k-steps mfma_f32_16x16x32_f16.
// MODE 1: h2s16 = fp16( dis[row] * (relu(acc+b) + xd16[row]*disi[row]) )
// MODE 0: C_f32 = acc + b

__device__ inline void ld32(const uint4* __restrict__ p, size_t idx,
                            float4& lo, float4& hi) {
    uint4 u = p[idx];
    float2 a = __half22float2(__builtin_bit_cast(__half2, u.x));
    float2 b = __half22float2(__builtin_bit_cast(__half2, u.y));
    float2 c = __half22float2(__builtin_bit_cast(__half2, u.z));
    float2 d = __half22float2(__builtin_bit_cast(__half2, u.w));
    lo = make_float4(a.x, a.y, b.x, b.y);
    hi = make_float4(c.x, c.y, d.x, d.y);
}

#define ACC8(l, h) do { \
    a0.x += l.x; a0.y += l.y; a0.z += l.z; a0.w += l.w; \
    a1.x += h.x; a1.y += h.y; a1.z += h.z; a1.w += h.w; } while (0)

template <int MODE>
__global__ __launch_bounds__(256, 7)
void k_fused(const int2* __restrict__ rs2, const int* __restrict__ csr_src,
             const float* __restrict__ dis, const float* __restrict__ disi,
             const __half* __restrict__ featd, const _Float16* __restrict__ Wf,
             const float* __restrict__ bias, void* __restrict__ C) {
    __shared__ __align__(16) _Float16 xs16[4 * 4 * 136];   // A-frag groups
    const int t = threadIdx.x;
    const int row0 = blockIdx.x * TILE;
    const uint4* f4p = (const uint4*)featd;  // row stride = 16 uint4

    {   // ---- gather phase: one full row per 16-lane group ----
        const int wave = t >> 6;          // 0..3
        const int g = (t >> 4) & 3;       // group in wave
        const int gl = t & 15;            // lane in group (owns 8 feats)
        const int r = wave * 4 + g;
        const int n = row0 + r;           // always < N_NODES (3125*16 exact)
        const int2 se = rs2[n];
        int j = se.x;
        const int je = se.y;
        float4 a0, a1;
        ld32(f4p, (size_t)n * 16 + gl, a0, a1);   // self loop
        for (; j + 7 < je; j += 8) {
            int s0 = csr_src[j],     s1 = csr_src[j + 1];
            int s2 = csr_src[j + 2], s3 = csr_src[j + 3];
            int s4 = csr_src[j + 4], s5 = csr_src[j + 5];
            int s6 = csr_src[j + 6], s7 = csr_src[j + 7];
            float4 l0, h0, l1, h1, l2, h2, l3, h3;
            float4 l4, h4, l5, h5, l6, h6, l7, h7;
            ld32(f4p, (size_t)s0 * 16 + gl, l0, h0);
            ld32(f4p, (size_t)s1 * 16 + gl, l1, h1);
            ld32(f4p, (size_t)s2 * 16 + gl, l2, h2);
            ld32(f4p, (size_t)s3 * 16 + gl, l3, h3);
            ld32(f4p, (size_t)s4 * 16 + gl, l4, h4);
            ld32(f4p, (size_t)s5 * 16 + gl, l5, h5);
            ld32(f4p, (size_t)s6 * 16 + gl, l6, h6);
            ld32(f4p, (size_t)s7 * 16 + gl, l7, h7);
            ACC8(l0, h0); ACC8(l1, h1); ACC8(l2, h2); ACC8(l3, h3);
            ACC8(l4, h4); ACC8(l5, h5); ACC8(l6, h6); ACC8(l7, h7);
        }
        for (; j + 3 < je; j += 4) {
            int s0 = csr_src[j],     s1 = csr_src[j + 1];
            int s2 = csr_src[j + 2], s3 = csr_src[j + 3];
            float4 l0, h0, l1, h1, l2, h2, l3, h3;
            ld32(f4p, (size_t)s0 * 16 + gl, l0, h0);
            ld32(f4p, (size_t)s1 * 16 + gl, l1, h1);
            ld32(f4p, (size_t)s2 * 16 + gl, l2, h2);
            ld32(f4p, (size_t)s3 * 16 + gl, l3, h3);
            ACC8(l0, h0); ACC8(l1, h1); ACC8(l2, h2); ACC8(l3, h3);
        }
        for (; j < je; ++j) {
            float4 l0, h0;
            ld32(f4p, (size_t)csr_src[j] * 16 + gl, l0, h0);
            ACC8(l0, h0);
        }
        const float dn = dis[n];
        const int s_ = gl >> 2, kb = gl & 3;
        half8v h;
        h[0] = (_Float16)(a0.x * dn); h[1] = (_Float16)(a0.y * dn);
        h[2] = (_Float16)(a0.z * dn); h[3] = (_Float16)(a0.w * dn);
        h[4] = (_Float16)(a1.x * dn); h[5] = (_Float16)(a1.y * dn);
        h[6] = (_Float16)(a1.z * dn); h[7] = (_Float16)(a1.w * dn);
        *(half8v*)(xs16 + (s_ * 4 + kb) * 136 + r * 8) = h;
    }
    __syncthreads();

    // ---- MFMA GEMM phase ----
    const int w = t >> 6;      // wave 0..3 -> cols 32w..32w+31
    const int l = t & 63;
    const int lc = l & 15;     // frag col / A row
    const int lk = l >> 4;     // k-block 0..3
    f32x4 acc[2];
    acc[0] = (f32x4)0.f; acc[1] = (f32x4)0.f;

#pragma unroll
    for (int s = 0; s < 4; s++) {
        half8v aF = *(half8v*)(xs16 + (s * 4 + lk) * 136 + lc * 8);
#pragma unroll
        for (int c = 0; c < 2; c++) {
            int ct = 2 * w + c;
            half8v bF = *(const half8v*)(Wf + (((ct * 4 + s) * 4 + lk) * 16 + lc) * 8);
            acc[c] = __builtin_amdgcn_mfma_f32_16x16x32_f16(aF, bF, acc[c], 0, 0, 0);
        }
    }

    // ---- epilogue ----
#pragma unroll
    for (int c = 0; c < 2; c++) {
        const int col = w * 32 + c * 16 + lc;
        const float bcol = bias[col];
#pragma unroll
        for (int j = 0; j < 4; j++) {
            const int row = row0 + lk * 4 + j;
            float v = acc[c][j] + bcol;
            if (MODE == 1) {
                float dn = dis[row];
                // skip = x = xd16 * sqrt(1+deg)  (validated round 16)
                float sk = __half2float(featd[(size_t)row * NF + col]) * disi[row];
                float o = dn * (fmaxf(v, 0.f) + sk);
                ((__half*)C)[(size_t)row * NF + col] = __float2half(o);
            } else {
                ((float*)C)[(size_t)row * NF + col] = v;
            }
        }
    }
}

// ---------------- launch ----------------

extern "C" void kernel_launch(void* const* d_in, const int* in_sizes, int n_in,
                              void* d_out, int out_size, void* d_ws, size_t ws_size,
                              hipStream_t stream) {
    const int*   ei = (const int*)d_in[0];
    const float* x  = (const float*)d_in[1];
    const float* W1 = (const float*)d_in[2];
    const float* b1 = (const float*)d_in[3];
    const float* W2 = (const float*)d_in[4];
    const float* b2 = (const float*)d_in[5];
    float* out = (float*)d_out;

    const int* src = ei;             // edge_index[0]
    const int* dst = ei + N_EDGES;   // edge_index[1]

    // workspace layout (~25.7 MB; NB*ECAP = 1000960 entries)
    char* w = (char*)d_ws;
    float*    dis     = (float*)(w);                    // [N]          200000
    int2*     rs2     = (int2*)  (w + 200704);          // [N] int2     400000
    int*      csr_src = (int*)   (w + 600832);          // [NB*ECAP]    4.00 MB
    int2*     ebuf    = (int2*)  (w + 4615168);         // [NB*ECAP]    8.01 MB
    __half*   h2s     = (__half*)(w + 12643328);        // [N*128] fp16 12.8 MB
    _Float16* wf1     = (_Float16*)(w + 25443584);      // 32 KB
    _Float16* wf2     = (_Float16*)(w + 25476352);      // 32 KB
    int*      bcur    = (int*)   (w + 25509120);        // [NB]
    float*    disi    = (float*)(w + 25510656);         // [N]          200000
    __half*   xd      = (__half*)out;                   // d_out as fp16 scratch

    const int fblk = N_NODES / TILE;                    // 3125 exact

    // CSR build (+wcvt riding) -> count/fill (+prescale riding)
    hipMemsetAsync(bcur, 0, NB * sizeof(int), stream);
    k_bplace<<<PBLKS + WCVT_BLKS, 256, 0, stream>>>(src, dst, bcur, ebuf,
                                                    W1, W2, wf1, wf2);
    k_count_fill<<<NB, 256, 0, stream>>>(bcur, ebuf, rs2, csr_src, dis, disi,
                                         x, xd);

    // layer 1: h2s = fp16(dis * (relu(gather(xd)@W1 + b1) + x))
    k_fused<1><<<fblk, 256, 0, stream>>>(rs2, csr_src, dis, disi, xd, wf1, b1, h2s);
    // layer 2: out = gather(h2s)@W2 + b2   (fp32 out)
    k_fused<0><<<fblk, 256, 0, stream>>>(rs2, csr_src, dis, disi, h2s, wf2, b2, out);
}

// Round 19
// 103.143 us; speedup vs baseline: 29.0502x; 1.0126x over previous
//
#include <hip/hip_runtime.h>
#include <hip/hip_fp16.h>

#define N_NODES 50000
#define N_EDGES 800000
#define NF 128
#define TILE 16                          // rows per fused block
#define NB 782                           // ceil(50000/64) dst-buckets
#define BSHIFT 6                         // 64 nodes per bucket
#define BNODES 64
#define ECAP 1280                        // bucket capacity (mean 1024, 8 sigma)
#define EPB 4096                         // edges per partition block
#define PBLKS ((N_EDGES + EPB - 1) / EPB)   // 196
#define WCVT_BLKS 128

typedef _Float16 half8v __attribute__((ext_vector_type(8)));
typedef float    f32x4  __attribute__((ext_vector_type(4)));

// ---------------- bucketed CSR build + W conversion ----------------
// blocks [0, PBLKS): partition edges into fixed-capacity dst-buckets
// blocks [PBLKS, PBLKS+WCVT_BLKS): W1/W2 -> fp16 B-fragment layout

__global__ __launch_bounds__(256)
void k_bplace(const int* __restrict__ src, const int* __restrict__ dst,
              int* __restrict__ bcur, int2* __restrict__ ebuf,
              const float* __restrict__ W1, const float* __restrict__ W2,
              _Float16* __restrict__ wf1, _Float16* __restrict__ wf2) {
    __shared__ int h[NB];
    const int t = threadIdx.x;
    if (blockIdx.x >= PBLKS) {       // ---- wcvt path (uniform per block) ----
        int i = (blockIdx.x - PBLKS) * 256 + t;   // 0..32767
        const float* W = (i < 16384) ? W1 : W2;
        _Float16* Wf = (i < 16384) ? wf1 : wf2;
        int j = i & 16383;
        int e = j & 7, col = (j >> 3) & 15, kb = (j >> 7) & 3,
            s = (j >> 9) & 3, ct = j >> 11;
        Wf[j] = (_Float16)W[(size_t)(s * 32 + kb * 8 + e) * NF + ct * 16 + col];
        return;
    }
    for (int i = t; i < NB; i += 256) h[i] = 0;
    __syncthreads();
    const int base4 = blockIdx.x * (EPB / 4);
#pragma unroll
    for (int k = 0; k < 4; k++) {
        int i4 = base4 + k * 256 + t;
        if (i4 < N_EDGES / 4) {
            int4 d = ((const int4*)dst)[i4];
            atomicAdd(&h[d.x >> BSHIFT], 1);
            atomicAdd(&h[d.y >> BSHIFT], 1);
            atomicAdd(&h[d.z >> BSHIFT], 1);
            atomicAdd(&h[d.w >> BSHIFT], 1);
        }
    }
    __syncthreads();
    for (int i = t; i < NB; i += 256)
        if (h[i]) h[i] = atomicAdd(&bcur[i], h[i]);   // count -> run base
    __syncthreads();
#pragma unroll
    for (int k = 0; k < 4; k++) {
        int i4 = base4 + k * 256 + t;
        if (i4 < N_EDGES / 4) {
            int4 d = ((const int4*)dst)[i4];
            int4 s = ((const int4*)src)[i4];
            int b_, p;
            b_ = d.x >> BSHIFT; p = min(atomicAdd(&h[b_], 1), ECAP - 1);
            ebuf[(size_t)b_ * ECAP + p] = make_int2(s.x, d.x);
            b_ = d.y >> BSHIFT; p = min(atomicAdd(&h[b_], 1), ECAP - 1);
            ebuf[(size_t)b_ * ECAP + p] = make_int2(s.y, d.y);
            b_ = d.z >> BSHIFT; p = min(atomicAdd(&h[b_], 1), ECAP - 1);
            ebuf[(size_t)b_ * ECAP + p] = make_int2(s.z, d.z);
            b_ = d.w >> BSHIFT; p = min(atomicAdd(&h[b_], 1), ECAP - 1);
            ebuf[(size_t)b_ * ECAP + p] = make_int2(s.w, d.w);
        }
    }
}

// one block per bucket (64 nodes, ~1024 edges): LDS count -> scan ->
// rs2/dis/disi + csr fill + fused prescale xd16 = fp16(dis * x)

__global__ __launch_bounds__(256)
void k_count_fill(const int* __restrict__ bcur, const int2* __restrict__ ebuf,
                  int2* __restrict__ rs2, int* __restrict__ csr_src,
                  float* __restrict__ dis, float* __restrict__ disi,
                  const float* __restrict__ x, __half* __restrict__ xd) {
    __shared__ int cnt[BNODES];
    __shared__ int ps[BNODES];
    __shared__ float sdis[BNODES];
    const int t = threadIdx.x;
    const int b = blockIdx.x;
    const int nbase = b << BSHIFT;
    const int nn = min(BNODES, N_NODES - nbase);
    if (t < BNODES) cnt[t] = 0;
    __syncthreads();
    const int e0 = b * ECAP;
    const int e1 = e0 + min(bcur[b], ECAP);
    for (int i = e0 + t; i < e1; i += 256)
        atomicAdd(&cnt[ebuf[i].y - nbase], 1);
    __syncthreads();
    const int a0 = (t < BNODES) ? cnt[t] : 0;
    if (t < BNODES) ps[t] = a0;
    __syncthreads();
    for (int off = 1; off < BNODES; off <<= 1) {   // 6 steps cover t<64
        int u = (t >= off && t < BNODES) ? ps[t - off] : 0;
        __syncthreads();
        if (t < BNODES) ps[t] += u;
        __syncthreads();
    }
    if (t < BNODES) {
        const int ex = ps[t] - a0;           // exclusive prefix
        if (t < nn) {
            float f = (float)(1 + a0);
            float d = rsqrtf(f);
            rs2[nbase + t] = make_int2(e0 + ex, e0 + ex + a0);
            dis[nbase + t] = d;
            disi[nbase + t] = sqrtf(f);
            sdis[t] = d;
        } else {
            sdis[t] = 0.f;
        }
        cnt[t] = ex;                         // bucket-local cursors
    }
    __syncthreads();
    for (int i = e0 + t; i < e1; i += 256) {
        int2 sd = ebuf[i];
        int p = atomicAdd(&cnt[sd.y - nbase], 1);
        csr_src[e0 + p] = sd.x;
    }
    // ---- fused prescale for this bucket's rows ----
    const int total = nn * 32;               // 32 float4 per row
    for (int idx = t; idx < total; idx += 256) {
        int r = idx >> 5, c = idx & 31;
        float d = sdis[r];
        float4 v = ((const float4*)x)[(size_t)(nbase + r) * 32 + c];
        union { __half2 h[2]; uint2 u; } pk;
        pk.h[0] = __floats2half2_rn(d * v.x, d * v.y);
        pk.h[1] = __floats2half2_rn(d * v.z, d * v.w);
        ((uint2*)xd)[(size_t)(nbase + r) * 32 + c] = pk.u;
    }
}

// ---------------- fused gather(fp16) + MFMA GEMM, TILE=16 ----------------
// (validated round 17)  Gather: 4 waves x 4 groups of 16 lanes; each group
// owns one full row concurrently; lane gl owns 8 feats (uint4). 8-deep
// unroll, no shuffle. A-frag store k = gl*8+e.
// GEMM: wave w -> cols 32w..32w+31, 4 k-steps mfma_f32_16x16x32_f16.
// MODE 1: h2s16 = fp16( dis[row] * (relu(acc+b) + xd16[row]*disi[row]) )
// MODE 0: C_f32 = acc + b

__device__ inline void ld32(const uint4* __restrict__ p, size_t idx,
                            float4& lo, float4& hi) {
    uint4 u = p[idx];
    float2 a = __half22float2(__builtin_bit_cast(__half2, u.x));
    float2 b = __half22float2(__builtin_bit_cast(__half2, u.y));
    float2 c = __half22float2(__builtin_bit_cast(__half2, u.z));
    float2 d = __half22float2(__builtin_bit_cast(__half2, u.w));
    lo = make_float4(a.x, a.y, b.x, b.y);
    hi = make_float4(c.x, c.y, d.x, d.y);
}

#define ACC8(l, h) do { \
    a0.x += l.x; a0.y += l.y; a0.z += l.z; a0.w += l.w; \
    a1.x += h.x; a1.y += h.y; a1.z += h.z; a1.w += h.w; } while (0)

template <int MODE>
__global__ __launch_bounds__(256, 7)
void k_fused(const int2* __restrict__ rs2, const int* __restrict__ csr_src,
             const float* __restrict__ dis, const float* __restrict__ disi,
             const __half* __restrict__ featd, const _Float16* __restrict__ Wf,
             const float* __restrict__ bias, void* __restrict__ C) {
    __shared__ __align__(16) _Float16 xs16[4 * 4 * 136];   // A-frag groups
    const int t = threadIdx.x;
    const int row0 = blockIdx.x * TILE;
    const uint4* f4p = (const uint4*)featd;  // row stride = 16 uint4

    {   // ---- gather phase: one full row per 16-lane group ----
        const int wave = t >> 6;          // 0..3
        const int g = (t >> 4) & 3;       // group in wave
        const int gl = t & 15;            // lane in group (owns 8 feats)
        const int r = wave * 4 + g;
        const int n = row0 + r;           // always < N_NODES (3125*16 exact)
        const int2 se = rs2[n];
        int j = se.x;
        const int je = se.y;
        float4 a0, a1;
        ld32(f4p, (size_t)n * 16 + gl, a0, a1);   // self loop
        for (; j + 7 < je; j += 8) {
            int s0 = csr_src[j],     s1 = csr_src[j + 1];
            int s2 = csr_src[j + 2], s3 = csr_src[j + 3];
            int s4 = csr_src[j + 4], s5 = csr_src[j + 5];
            int s6 = csr_src[j + 6], s7 = csr_src[j + 7];
            float4 l0, h0, l1, h1, l2, h2, l3, h3;
            float4 l4, h4, l5, h5, l6, h6, l7, h7;
            ld32(f4p, (size_t)s0 * 16 + gl, l0, h0);
            ld32(f4p, (size_t)s1 * 16 + gl, l1, h1);
            ld32(f4p, (size_t)s2 * 16 + gl, l2, h2);
            ld32(f4p, (size_t)s3 * 16 + gl, l3, h3);
            ld32(f4p, (size_t)s4 * 16 + gl, l4, h4);
            ld32(f4p, (size_t)s5 * 16 + gl, l5, h5);
            ld32(f4p, (size_t)s6 * 16 + gl, l6, h6);
            ld32(f4p, (size_t)s7 * 16 + gl, l7, h7);
            ACC8(l0, h0); ACC8(l1, h1); ACC8(l2, h2); ACC8(l3, h3);
            ACC8(l4, h4); ACC8(l5, h5); ACC8(l6, h6); ACC8(l7, h7);
        }
        for (; j + 3 < je; j += 4) {
            int s0 = csr_src[j],     s1 = csr_src[j + 1];
            int s2 = csr_src[j + 2], s3 = csr_src[j + 3];
            float4 l0, h0, l1, h1, l2, h2, l3, h3;
            ld32(f4p, (size_t)s0 * 16 + gl, l0, h0);
            ld32(f4p, (size_t)s1 * 16 + gl, l1, h1);
            ld32(f4p, (size_t)s2 * 16 + gl, l2, h2);
            ld32(f4p, (size_t)s3 * 16 + gl, l3, h3);
            ACC8(l0, h0); ACC8(l1, h1); ACC8(l2, h2); ACC8(l3, h3);
        }
        for (; j < je; ++j) {
            float4 l0, h0;
            ld32(f4p, (size_t)csr_src[j] * 16 + gl, l0, h0);
            ACC8(l0, h0);
        }
        const float dn = dis[n];
        const int s_ = gl >> 2, kb = gl & 3;
        half8v h;
        h[0] = (_Float16)(a0.x * dn); h[1] = (_Float16)(a0.y * dn);
        h[2] = (_Float16)(a0.z * dn); h[3] = (_Float16)(a0.w * dn);
        h[4] = (_Float16)(a1.x * dn); h[5] = (_Float16)(a1.y * dn);
        h[6] = (_Float16)(a1.z * dn); h[7] = (_Float16)(a1.w * dn);
        *(half8v*)(xs16 + (s_ * 4 + kb) * 136 + r * 8) = h;
    }
    __syncthreads();

    // ---- MFMA GEMM phase ----
    const int w = t >> 6;      // wave 0..3 -> cols 32w..32w+31
    const int l = t & 63;
    const int lc = l & 15;     // frag col / A row
    const int lk = l >> 4;     // k-block 0..3
    f32x4 acc[2];
    acc[0] = (f32x4)0.f; acc[1] = (f32x4)0.f;

#pragma unroll
    for (int s = 0; s < 4; s++) {
        half8v aF = *(half8v*)(xs16 + (s * 4 + lk) * 136 + lc * 8);
#pragma unroll
        for (int c = 0; c < 2; c++) {
            int ct = 2 * w + c;
            half8v bF = *(const half8v*)(Wf + (((ct * 4 + s) * 4 + lk) * 16 + lc) * 8);
            acc[c] = __builtin_amdgcn_mfma_f32_16x16x32_f16(aF, bF, acc[c], 0, 0, 0);
        }
    }

    // ---- epilogue ----
#pragma unroll
    for (int c = 0; c < 2; c++) {
        const int col = w * 32 + c * 16 + lc;
        const float bcol = bias[col];
#pragma unroll
        for (int j = 0; j < 4; j++) {
            const int row = row0 + lk * 4 + j;
            float v = acc[c][j] + bcol;
            if (MODE == 1) {
                float dn = dis[row];
                // skip = x = xd16 * sqrt(1+deg)  (validated round 16)
                float sk = __half2float(featd[(size_t)row * NF + col]) * disi[row];
                float o = dn * (fmaxf(v, 0.f) + sk);
                ((__half*)C)[(size_t)row * NF + col] = __float2half(o);
            } else {
                ((float*)C)[(size_t)row * NF + col] = v;
            }
        }
    }
}

// ---------------- launch ----------------

extern "C" void kernel_launch(void* const* d_in, const int* in_sizes, int n_in,
                              void* d_out, int out_size, void* d_ws, size_t ws_size,
                              hipStream_t stream) {
    const int*   ei = (const int*)d_in[0];
    const float* x  = (const float*)d_in[1];
    const float* W1 = (const float*)d_in[2];
    const float* b1 = (const float*)d_in[3];
    const float* W2 = (const float*)d_in[4];
    const float* b2 = (const float*)d_in[5];
    float* out = (float*)d_out;

    const int* src = ei;             // edge_index[0]
    const int* dst = ei + N_EDGES;   // edge_index[1]

    // workspace layout (~25.7 MB; NB*ECAP = 1000960 entries)
    char* w = (char*)d_ws;
    float*    dis     = (float*)(w);                    // [N]          200000
    int2*     rs2     = (int2*)  (w + 200704);          // [N] int2     400000
    int*      csr_src = (int*)   (w + 600832);          // [NB*ECAP]    4.00 MB
    int2*     ebuf    = (int2*)  (w + 4615168);         // [NB*ECAP]    8.01 MB
    __half*   h2s     = (__half*)(w + 12643328);        // [N*128] fp16 12.8 MB
    _Float16* wf1     = (_Float16*)(w + 25443584);      // 32 KB
    _Float16* wf2     = (_Float16*)(w + 25476352);      // 32 KB
    int*      bcur    = (int*)   (w + 25509120);        // [NB] 3128 B
    float*    disi    = (float*)(w + 25513216);         // [N]          200000
    __half*   xd      = (__half*)out;                   // d_out as fp16 scratch

    const int fblk = N_NODES / TILE;                    // 3125 exact

    // CSR build (+wcvt riding) -> count/fill (+prescale riding)
    hipMemsetAsync(bcur, 0, NB * sizeof(int), stream);
    k_bplace<<<PBLKS + WCVT_BLKS, 256, 0, stream>>>(src, dst, bcur, ebuf,
                                                    W1, W2, wf1, wf2);
    k_count_fill<<<NB, 256, 0, stream>>>(bcur, ebuf, rs2, csr_src, dis, disi,
                                         x, xd);

    // layer 1: h2s = fp16(dis * (relu(gather(xd)@W1 + b1) + x))
    k_fused<1><<<fblk, 256, 0, stream>>>(rs2, csr_src, dis, disi, xd, wf1, b1, h2s);
    // layer 2: out = gather(h2s)@W2 + b2   (fp32 out)
    k_fused<0><<<fblk, 256, 0, stream>>>(rs2, csr_src, dis, disi, h2s, wf2, b2, out);
}